// Round 1
// baseline (7564.114 us; speedup 1.0000x reference)
//
#include <hip/hip_runtime.h>
#include <stdint.h>

#define H    128
#define NBAT 128
#define AD   256
#define NP   65536
#define NL   32768
#define NG   131072

typedef __attribute__((ext_vector_type(8))) short short8;
typedef __attribute__((ext_vector_type(4))) float f32x4;

__device__ __forceinline__ ushort f2bf(float f) {
    uint32_t u = __float_as_uint(f);
    u += 0x7FFFu + ((u >> 16) & 1u);
    return (ushort)(u >> 16);
}
__device__ __forceinline__ float bf2f(ushort h) {
    return __uint_as_float(((uint32_t)h) << 16);
}

// ---------------- weight prep: bf16 transposed [n][k] copies + sums ----------
__global__ void prep_w(const float* __restrict__ Wl1, const float* __restrict__ Wr1,
                       const float* __restrict__ bl1,
                       const float* __restrict__ Wl2, const float* __restrict__ Wr2,
                       const float* __restrict__ bl2,
                       ushort* __restrict__ wlt,  // [2][7][128*128] (n-major)
                       float* __restrict__ bsum)  // [2][256]: [l][0:128]=blp, [l][128:256]=blg
{
    int m = blockIdx.x;
    if (m < 14) {
        int l = m / 7, r = m % 7;
        const float* Wl = l ? Wl2 : Wl1;
        const float* Wr = l ? Wr2 : Wr1;
        ushort* dst = wlt + (size_t)m * 16384;
        for (int it = 0; it < 64; ++it) {
            int idx = it * 256 + threadIdx.x;
            int k = idx >> 7, n = idx & 127;
            float v;
            if (r < 5)       v = Wl[r * 16384 + k * 128 + n];
            else if (r == 5) v = Wr[0 * 16384 + k * 128 + n] + Wr[1 * 16384 + k * 128 + n]
                               + Wr[2 * 16384 + k * 128 + n];
            else             v = Wr[3 * 16384 + k * 128 + n] + Wr[4 * 16384 + k * 128 + n];
            dst[n * 128 + k] = f2bf(v);
        }
    } else {
        int t = threadIdx.x;
        if (t < 128) {
            bsum[0 * 256 + t]       = bl1[0 * 128 + t] + bl1[1 * 128 + t] + bl1[2 * 128 + t];
            bsum[0 * 256 + 128 + t] = bl1[3 * 128 + t] + bl1[4 * 128 + t];
            bsum[1 * 256 + t]       = bl2[0 * 128 + t] + bl2[1 * 128 + t] + bl2[2 * 128 + t];
            bsum[1 * 256 + 128 + t] = bl2[3 * 128 + t] + bl2[4 * 128 + t];
        }
    }
}

// ---------------- encoders: h = relu(x @ W + b) -> bf16 ----------------------
__global__ void encode_k(const float* __restrict__ x, const float* __restrict__ W,
                         const float* __restrict__ b, ushort* __restrict__ out, int K)
{
    int t = threadIdx.x;
    int i = blockIdx.x * 2 + (t >> 7);
    int c = t & 127;
    float acc = b[c];
    for (int k = 0; k < K; ++k) acc += x[(size_t)i * K + k] * W[k * 128 + c];
    out[(size_t)i * 128 + c] = f2bf(fmaxf(acc, 0.f));
}

// ---------------- per-destination edge counts --------------------------------
__global__ void count_k(const int* __restrict__ dst, float* __restrict__ cnt, int E)
{
    int e = blockIdx.x * 256 + threadIdx.x;
    if (e < E) atomicAdd(&cnt[dst[e]], 1.0f);
}

// ---------------- scatter-add bf16 rows into fp32 accumulator ----------------
__global__ void scatter_k(const ushort* __restrict__ h, const int* __restrict__ src,
                          const int* __restrict__ dst, float* __restrict__ agg, int E)
{
    int tid = blockIdx.x * 256 + threadIdx.x;
    int e = tid >> 5;
    if (e >= E) return;
    int q = (tid & 31) * 4;
    int s = src[e], d = dst[e];
    const ushort4 v = *(const ushort4*)(h + (size_t)s * 128 + q);
    float* p = agg + (size_t)d * 128 + q;
    atomicAdd(p + 0, bf2f(v.x));
    atomicAdd(p + 1, bf2f(v.y));
    atomicAdd(p + 2, bf2f(v.z));
    atomicAdd(p + 3, bf2f(v.w));
}

// ---------------- divide by count, convert to bf16 ---------------------------
__global__ void finish_k(const float* __restrict__ agg, const float* __restrict__ cnt,
                         ushort* __restrict__ out, int N)
{
    int tid = blockIdx.x * 256 + threadIdx.x;
    int i = tid >> 5;
    if (i >= N) return;
    int q = (tid & 31) * 4;
    float inv = 1.0f / fmaxf(cnt[i], 1.0f);
    const float4 v = *(const float4*)(agg + (size_t)i * 128 + q);
    ushort4 o;
    o.x = f2bf(v.x * inv); o.y = f2bf(v.y * inv);
    o.z = f2bf(v.z * inv); o.w = f2bf(v.w * inv);
    *(ushort4*)(out + (size_t)i * 128 + q) = o;
}

// ---------------- multi-source GEMM: out = relu(sum_i A_i @ W_i + bias) ------
// A_i: [M,128] bf16 row-major.  W_i: [128n][128k] bf16 (pre-transposed).
// out: [M,128] bf16.  In-place (out == some A_i) is safe: blocks only touch
// their own 128-row slice and all reads precede the epilogue writes.
__launch_bounds__(256, 2)
__global__ void gemm_k(const ushort* __restrict__ A0, const ushort* __restrict__ A1,
                       const ushort* __restrict__ A2, const ushort* __restrict__ A3,
                       const ushort* __restrict__ W0, const ushort* __restrict__ W1,
                       const ushort* __restrict__ W2, const ushort* __restrict__ W3,
                       const float* __restrict__ bias, ushort* __restrict__ out, int nsrc)
{
    __shared__ ushort a_lds[128][72];
    __shared__ ushort w_lds[128][72];
    const int tid = threadIdx.x;
    const int lane = tid & 63, wave = tid >> 6;
    const int wr = wave >> 1, wc = wave & 1;
    const size_t r0 = (size_t)blockIdx.x * 128;

    f32x4 acc[4][4];
    const f32x4 zero = {0.f, 0.f, 0.f, 0.f};
#pragma unroll
    for (int m = 0; m < 4; ++m)
#pragma unroll
        for (int n = 0; n < 4; ++n) acc[m][n] = zero;

    const ushort* As[4] = {A0, A1, A2, A3};
    const ushort* Ws[4] = {W0, W1, W2, W3};

    for (int s = 0; s < nsrc; ++s) {
        const ushort* Ap = As[s] + r0 * 128;
        const ushort* Wp = Ws[s];
        for (int k0 = 0; k0 < 128; k0 += 64) {
            __syncthreads();
#pragma unroll
            for (int j = 0; j < 4; ++j) {
                int idx = (j * 256 + tid) * 8;
                int r = idx >> 6, c = idx & 63;
                *(uint4*)&a_lds[r][c] = *(const uint4*)(Ap + r * 128 + k0 + c);
                *(uint4*)&w_lds[r][c] = *(const uint4*)(Wp + r * 128 + k0 + c);
            }
            __syncthreads();
#pragma unroll
            for (int ks = 0; ks < 64; ks += 32) {
                short8 af[4], bfr[4];
                int col = ks + ((lane >> 4) << 3);
                int ra = (wr << 6) + (lane & 15);
                int rb = (wc << 6) + (lane & 15);
#pragma unroll
                for (int m = 0; m < 4; ++m) af[m] = *(const short8*)&a_lds[ra + m * 16][col];
#pragma unroll
                for (int n = 0; n < 4; ++n) bfr[n] = *(const short8*)&w_lds[rb + n * 16][col];
#pragma unroll
                for (int m = 0; m < 4; ++m)
#pragma unroll
                    for (int n = 0; n < 4; ++n)
                        acc[m][n] = __builtin_amdgcn_mfma_f32_16x16x32_bf16(
                            af[m], bfr[n], acc[m][n], 0, 0, 0);
            }
        }
    }

    const int rbase = (wr << 6) + ((lane >> 4) << 2);
    const int cbase = (wc << 6) + (lane & 15);
#pragma unroll
    for (int m = 0; m < 4; ++m)
#pragma unroll
        for (int n = 0; n < 4; ++n) {
            int coln = cbase + n * 16;
            float bcol = bias[coln];
#pragma unroll
            for (int rg = 0; rg < 4; ++rg) {
                int row = rbase + m * 16 + rg;
                float v = acc[m][n][rg] + bcol;
                v = fmaxf(v, 0.f);
                out[(r0 + row) * 128 + coln] = f2bf(v);
            }
        }
}

// ---------------- pooling gate: gate[i] = h_p[i]·Wg + bg; segment max --------
__global__ void gate_k(const ushort* __restrict__ hp, const float* __restrict__ Wg,
                       const float* __restrict__ bg, const int* __restrict__ batch,
                       float* __restrict__ gate, unsigned* __restrict__ mbuf)
{
    int lane = threadIdx.x & 63;
    int wave = threadIdx.x >> 6;
    int i = blockIdx.x * 4 + wave;
    ushort2 h2 = *(const ushort2*)(hp + (size_t)i * 128 + lane * 2);
    float2 w2 = *(const float2*)(Wg + lane * 2);
    float g = bf2f(h2.x) * w2.x + bf2f(h2.y) * w2.y;
    for (int off = 32; off; off >>= 1) g += __shfl_down(g, off);
    if (lane == 0) {
        float gv = g + bg[0];
        gate[i] = gv;
        uint32_t u = __float_as_uint(gv);
        unsigned enc = (u & 0x80000000u) ? ~u : (u | 0x80000000u);
        atomicMax(&mbuf[batch[i]], enc);
    }
}

// ---------------- segment softmax + weighted sum -> emb[B,128] ---------------
__global__ void pool_k(const float* __restrict__ gate, const ushort* __restrict__ hp,
                       const int* __restrict__ batch, const unsigned* __restrict__ mbuf,
                       float* __restrict__ ew, float* __restrict__ emb)
{
    __shared__ float red[256];
    __shared__ int sb[2];
    __shared__ float sden;
    int b = blockIdx.x, t = threadIdx.x;
    if (t == 0) {
        int lo = 0, hi = NP;
        while (lo < hi) { int mid = (lo + hi) >> 1; if (batch[mid] < b) lo = mid + 1; else hi = mid; }
        sb[0] = lo;
        lo = 0; hi = NP;
        while (lo < hi) { int mid = (lo + hi) >> 1; if (batch[mid] < b + 1) lo = mid + 1; else hi = mid; }
        sb[1] = lo;
    }
    __syncthreads();
    int s = sb[0], e = sb[1];
    unsigned enc = mbuf[b];
    uint32_t mu = (enc & 0x80000000u) ? (enc & 0x7FFFFFFFu) : ~enc;
    float m = __uint_as_float(mu);

    float loc = 0.f;
    for (int i = s + t; i < e; i += 256) {
        float w = expf(gate[i] - m);
        ew[i] = w;
        loc += w;
    }
    red[t] = loc; __syncthreads();
    for (int o = 128; o; o >>= 1) { if (t < o) red[t] += red[t + o]; __syncthreads(); }
    if (t == 0) sden = red[0];
    __syncthreads();
    float inv = (e > s) ? 1.0f / sden : 0.f;

    int c = t & 127, half = t >> 7;
    float acc = 0.f;
    for (int i = s + half; i < e; i += 2) acc += ew[i] * bf2f(hp[(size_t)i * 128 + c]);
    __syncthreads();
    red[t] = acc; __syncthreads();
    if (t < 128) emb[b * 128 + c] = (red[c] + red[c + 128]) * inv;
}

// ---------------- actor/critic heads ----------------------------------------
__global__ void heads_k(const float* __restrict__ emb,
                        const float* __restrict__ Wa1, const float* __restrict__ ba1,
                        const float* __restrict__ Wa2, const float* __restrict__ ba2,
                        const float* __restrict__ Wc1, const float* __restrict__ bc1,
                        const float* __restrict__ Wc2, const float* __restrict__ bc2,
                        float* __restrict__ outL, float* __restrict__ outV)
{
    __shared__ float er[128], ha[128], hc[128], red[128];
    int b = blockIdx.x, t = threadIdx.x;
    if (t < 128) er[t] = emb[b * 128 + t];
    __syncthreads();
    if (t < 128) {
        float a = ba1[t];
        for (int k = 0; k < 128; ++k) a += er[k] * Wa1[k * 128 + t];
        ha[t] = fmaxf(a, 0.f);
    } else {
        int c = t - 128;
        float a = bc1[c];
        for (int k = 0; k < 128; ++k) a += er[k] * Wc1[k * 128 + c];
        hc[c] = fmaxf(a, 0.f);
    }
    __syncthreads();
    {
        float a = ba2[t];
        for (int k = 0; k < 128; ++k) a += ha[k] * Wa2[k * 256 + t];
        outL[b * 256 + t] = a;
    }
    if (t < 128) red[t] = hc[t] * Wc2[t];
    __syncthreads();
    for (int o = 64; o; o >>= 1) { if (t < o) red[t] += red[t + o]; __syncthreads(); }
    if (t == 0) outV[b] = red[0] + bc2[0];
}

// ============================================================================
extern "C" void kernel_launch(void* const* d_in, const int* in_sizes, int n_in,
                              void* d_out, int out_size, void* d_ws, size_t ws_size,
                              hipStream_t stream)
{
    const float* x_phys = (const float*)d_in[0];
    const float* x_log  = (const float*)d_in[1];
    const float* x_gate = (const float*)d_in[2];
    const int*   batch  = (const int*)d_in[3];
    const int* intra_s = (const int*)d_in[4];  const int* intra_d = (const int*)d_in[5];
    const int* inter_s = (const int*)d_in[6];  const int* inter_d = (const int*)d_in[7];
    const int* map_s   = (const int*)d_in[8];  const int* map_d   = (const int*)d_in[9];
    const int* part_s  = (const int*)d_in[10]; const int* part_d  = (const int*)d_in[11];
    const int* dep_s   = (const int*)d_in[12]; const int* dep_d   = (const int*)d_in[13];
    const int E_INTRA = in_sizes[4], E_INTER = in_sizes[6], E_MAP = in_sizes[8],
              E_PART = in_sizes[10], E_DEP = in_sizes[12];

    const float* W_phys = (const float*)d_in[14]; const float* b_phys = (const float*)d_in[15];
    const float* W_log  = (const float*)d_in[16]; const float* b_log  = (const float*)d_in[17];
    const float* W_gate = (const float*)d_in[18]; const float* b_gate = (const float*)d_in[19];
    const float* Wl1 = (const float*)d_in[20]; const float* bl1 = (const float*)d_in[21];
    const float* Wr1 = (const float*)d_in[22];
    const float* Wl2 = (const float*)d_in[23]; const float* bl2 = (const float*)d_in[24];
    const float* Wr2 = (const float*)d_in[25];
    const float* Wg  = (const float*)d_in[26]; const float* bg  = (const float*)d_in[27];
    const float* Wa1 = (const float*)d_in[28]; const float* ba1 = (const float*)d_in[29];
    const float* Wa2 = (const float*)d_in[30]; const float* ba2 = (const float*)d_in[31];
    const float* Wc1 = (const float*)d_in[32]; const float* bc1 = (const float*)d_in[33];
    const float* Wc2 = (const float*)d_in[34]; const float* bc2 = (const float*)d_in[35];

    float* outL = (float*)d_out;
    float* outV = outL + NBAT * AD;

    // ---- carve workspace ----
    char* wsp = (char*)d_ws;
    size_t off = 0;
    auto alloc = [&](size_t sz) -> void* {
        void* p = wsp + off;
        off = (off + sz + 255) & ~(size_t)255;
        return p;
    };
    ushort* hp       = (ushort*)alloc((size_t)NP * 128 * 2);
    ushort* hl       = (ushort*)alloc((size_t)NL * 128 * 2);
    ushort* hg       = (ushort*)alloc((size_t)NG * 128 * 2);
    ushort* aggbA    = (ushort*)alloc((size_t)NP * 128 * 2);  // intra mean
    ushort* aggbB    = (ushort*)alloc((size_t)NP * 128 * 2);  // inter mean
    ushort* Mmap     = (ushort*)alloc((size_t)NP * 128 * 2);  // mean(h_l) over map
    ushort* aggbD    = (ushort*)alloc((size_t)NG * 128 * 2);  // dep mean
    ushort* Mpart    = (ushort*)alloc((size_t)NG * 128 * 2);  // mean(h_l) over part
    float*  scratch  = (float*)alloc((size_t)NG * 128 * 4);   // fp32 scatter accumulator
    float*  cnts     = (float*)alloc((size_t)(3 * NP + 2 * NG) * 4);
    float* cnt_intra = cnts;
    float* cnt_inter = cnts + NP;
    float* cnt_map   = cnts + 2 * NP;
    float* cnt_part  = cnts + 3 * NP;
    float* cnt_dep   = cnts + 3 * NP + NG;
    float*    gate  = (float*)alloc((size_t)NP * 4);
    float*    ew    = (float*)alloc((size_t)NP * 4);
    unsigned* mbuf  = (unsigned*)alloc(NBAT * 4);
    float*    emb   = (float*)alloc(NBAT * 128 * 4);
    ushort*   wlt   = (ushort*)alloc((size_t)2 * 7 * 16384 * 2);
    float*    bsum  = (float*)alloc(2 * 256 * 4);
    (void)ws_size; (void)out_size; (void)n_in;

    // ---- weight prep + encoders ----
    prep_w<<<15, 256, 0, stream>>>(Wl1, Wr1, bl1, Wl2, Wr2, bl2, wlt, bsum);
    encode_k<<<NP / 2, 256, 0, stream>>>(x_phys, W_phys, b_phys, hp, 5);
    encode_k<<<NL / 2, 256, 0, stream>>>(x_log, W_log, b_log, hl, 1);
    encode_k<<<NG / 2, 256, 0, stream>>>(x_gate, W_gate, b_gate, hg, 2);

    // ---- edge counts ----
    hipMemsetAsync(cnts, 0, (size_t)(3 * NP + 2 * NG) * 4, stream);
    count_k<<<(E_INTRA + 255) / 256, 256, 0, stream>>>(intra_d, cnt_intra, E_INTRA);
    count_k<<<(E_INTER + 255) / 256, 256, 0, stream>>>(inter_d, cnt_inter, E_INTER);
    count_k<<<(E_MAP + 255) / 256, 256, 0, stream>>>(map_d, cnt_map, E_MAP);
    count_k<<<(E_PART + 255) / 256, 256, 0, stream>>>(part_d, cnt_part, E_PART);
    count_k<<<(E_DEP + 255) / 256, 256, 0, stream>>>(dep_d, cnt_dep, E_DEP);

    // ---- static aggregations from h_l (reused by both layers) ----
    hipMemsetAsync(scratch, 0, (size_t)NP * 128 * 4, stream);
    scatter_k<<<E_MAP * 32 / 256, 256, 0, stream>>>(hl, map_s, map_d, scratch, E_MAP);
    finish_k<<<NP / 8, 256, 0, stream>>>(scratch, cnt_map, Mmap, NP);

    hipMemsetAsync(scratch, 0, (size_t)NG * 128 * 4, stream);
    scatter_k<<<E_PART * 32 / 256, 256, 0, stream>>>(hl, part_s, part_d, scratch, E_PART);
    finish_k<<<NG / 8, 256, 0, stream>>>(scratch, cnt_part, Mpart, NG);

    // ---- two hetero layers ----
    for (int l = 0; l < 2; ++l) {
        const ushort* wl = wlt + (size_t)l * 7 * 16384;
        const float* blp = bsum + l * 256;
        const float* blg = blp + 128;

        hipMemsetAsync(scratch, 0, (size_t)NP * 128 * 4, stream);
        scatter_k<<<E_INTRA * 32 / 256, 256, 0, stream>>>(hp, intra_s, intra_d, scratch, E_INTRA);
        finish_k<<<NP / 8, 256, 0, stream>>>(scratch, cnt_intra, aggbA, NP);

        hipMemsetAsync(scratch, 0, (size_t)NP * 128 * 4, stream);
        scatter_k<<<E_INTER * 32 / 256, 256, 0, stream>>>(hp, inter_s, inter_d, scratch, E_INTER);
        finish_k<<<NP / 8, 256, 0, stream>>>(scratch, cnt_inter, aggbB, NP);

        hipMemsetAsync(scratch, 0, (size_t)NG * 128 * 4, stream);
        scatter_k<<<E_DEP * 32 / 256, 256, 0, stream>>>(hg, dep_s, dep_d, scratch, E_DEP);
        finish_k<<<NG / 8, 256, 0, stream>>>(scratch, cnt_dep, aggbD, NG);

        // out_p = relu(meanI@Wl0 + meanT@Wl1 + Mmap@Wl2 + hp@(Wr0+Wr1+Wr2) + blp)
        gemm_k<<<NP / 128, 256, 0, stream>>>(aggbA, aggbB, Mmap, hp,
                                             wl + 0 * 16384, wl + 1 * 16384,
                                             wl + 2 * 16384, wl + 5 * 16384,
                                             blp, hp, 4);
        // out_g = relu(Mpart@Wl3 + meanD@Wl4 + hg@(Wr3+Wr4) + blg)
        gemm_k<<<NG / 128, 256, 0, stream>>>(Mpart, aggbD, hg, nullptr,
                                             wl + 3 * 16384, wl + 4 * 16384,
                                             wl + 6 * 16384, nullptr,
                                             blg, hg, 3);
    }

    // ---- attentional pooling + heads ----
    hipMemsetAsync(mbuf, 0, NBAT * 4, stream);
    gate_k<<<NP / 4, 256, 0, stream>>>(hp, Wg, bg, batch, gate, mbuf);
    pool_k<<<NBAT, 256, 0, stream>>>(gate, hp, batch, mbuf, ew, emb);
    heads_k<<<NBAT, 256, 0, stream>>>(emb, Wa1, ba1, Wa2, ba2, Wc1, bc1, Wc2, bc2, outL, outV);
}

// Round 4
// 2058.788 us; speedup vs baseline: 3.6741x; 3.6741x over previous
//
#include <hip/hip_runtime.h>
#include <stdint.h>

#define H    128
#define NBAT 128
#define AD   256
#define NP   65536
#define NL   32768
#define NG   131072

typedef __attribute__((ext_vector_type(8))) short short8;
typedef __attribute__((ext_vector_type(4))) float f32x4;

__device__ __forceinline__ ushort f2bf(float f) {
    uint32_t u = __float_as_uint(f);
    u += 0x7FFFu + ((u >> 16) & 1u);
    return (ushort)(u >> 16);
}
__device__ __forceinline__ float bf2f(ushort h) {
    return __uint_as_float(((uint32_t)h) << 16);
}
__device__ __forceinline__ float bflo(uint32_t v) { return __uint_as_float(v << 16); }
__device__ __forceinline__ float bfhi(uint32_t v) { return __uint_as_float(v & 0xFFFF0000u); }

// ---------------- weight prep: bf16 transposed [n][k] copies + sums ----------
__global__ void prep_w(const float* __restrict__ Wl1, const float* __restrict__ Wr1,
                       const float* __restrict__ bl1,
                       const float* __restrict__ Wl2, const float* __restrict__ Wr2,
                       const float* __restrict__ bl2,
                       ushort* __restrict__ wlt,  // [2][7][128*128] (n-major)
                       float* __restrict__ bsum)  // [2][256]
{
    int m = blockIdx.x;
    if (m < 14) {
        int l = m / 7, r = m % 7;
        const float* Wl = l ? Wl2 : Wl1;
        const float* Wr = l ? Wr2 : Wr1;
        ushort* dst = wlt + (size_t)m * 16384;
        for (int it = 0; it < 64; ++it) {
            int idx = it * 256 + threadIdx.x;
            int k = idx >> 7, n = idx & 127;
            float v;
            if (r < 5)       v = Wl[r * 16384 + k * 128 + n];
            else if (r == 5) v = Wr[0 * 16384 + k * 128 + n] + Wr[1 * 16384 + k * 128 + n]
                               + Wr[2 * 16384 + k * 128 + n];
            else             v = Wr[3 * 16384 + k * 128 + n] + Wr[4 * 16384 + k * 128 + n];
            dst[n * 128 + k] = f2bf(v);
        }
    } else {
        int t = threadIdx.x;
        if (t < 128) {
            bsum[0 * 256 + t]       = bl1[0 * 128 + t] + bl1[1 * 128 + t] + bl1[2 * 128 + t];
            bsum[0 * 256 + 128 + t] = bl1[3 * 128 + t] + bl1[4 * 128 + t];
            bsum[1 * 256 + t]       = bl2[0 * 128 + t] + bl2[1 * 128 + t] + bl2[2 * 128 + t];
            bsum[1 * 256 + 128 + t] = bl2[3 * 128 + t] + bl2[4 * 128 + t];
        }
    }
}

// ---------------- encoders: h = relu(x @ W + b) -> bf16 ----------------------
__global__ void encode_k(const float* __restrict__ x, const float* __restrict__ W,
                         const float* __restrict__ b, ushort* __restrict__ out, int K)
{
    int t = threadIdx.x;
    int i = blockIdx.x * 2 + (t >> 7);
    int c = t & 127;
    float acc = b[c];
    for (int k = 0; k < K; ++k) acc += x[(size_t)i * K + k] * W[k * 128 + c];
    out[(size_t)i * 128 + c] = f2bf(fmaxf(acc, 0.f));
}

// ---------------- CSR build: histogram -> scan -> fill -----------------------
__global__ void hist_k(const int* __restrict__ dst, int* __restrict__ hist, int E)
{
    int e = blockIdx.x * 256 + threadIdx.x;
    if (e < E) atomicAdd(&hist[dst[e]], 1);
}

// single-block exclusive scan of hist[N] -> rowptr[N+1], copy into fill[]
__global__ void scan_k(const int* __restrict__ hist, int* __restrict__ rowptr,
                       int* __restrict__ fill, int N)
{
    __shared__ int lds[1024];
    int t = threadIdx.x;
    int C = N >> 10;              // N is 65536 or 131072 -> C = 64 / 128
    int base = t * C;
    int s = 0;
    for (int j = 0; j < C; ++j) s += hist[base + j];
    lds[t] = s;
    __syncthreads();
    for (int d = 1; d < 1024; d <<= 1) {
        int v = (t >= d) ? lds[t - d] : 0;
        __syncthreads();
        lds[t] += v;
        __syncthreads();
    }
    int run = (t == 0) ? 0 : lds[t - 1];
    for (int j = 0; j < C; ++j) {
        int hv = hist[base + j];
        rowptr[base + j] = run;
        fill[base + j] = run;
        run += hv;
    }
    if (t == 1023) rowptr[N] = run;
}

__global__ void fill_k(const int* __restrict__ src, const int* __restrict__ dst,
                       int* __restrict__ fill, int* __restrict__ ssrc, int E)
{
    int e = blockIdx.x * 256 + threadIdx.x;
    if (e < E) {
        int p = atomicAdd(&fill[dst[e]], 1);
        ssrc[p] = src[e];
    }
}

// ---------------- gather-mean: one wave per destination node -----------------
// out[i] = mean over edge list of h[src] rows (bf16 in, bf16 out, fp32 accum)
__global__ void gather_mean_k(const ushort* __restrict__ h, const int* __restrict__ rowptr,
                              const int* __restrict__ ssrc, ushort* __restrict__ out, int N)
{
    int i = blockIdx.x * 4 + (threadIdx.x >> 6);
    int lane = threadIdx.x & 63;
    int s0 = rowptr[i], s1 = rowptr[i + 1];
    float a0 = 0.f, a1 = 0.f;
    int e = s0;
    for (; e + 4 <= s1; e += 4) {
        int j0 = ssrc[e], j1 = ssrc[e + 1], j2 = ssrc[e + 2], j3 = ssrc[e + 3];
        uint32_t v0 = *(const uint32_t*)(h + (size_t)j0 * 128 + lane * 2);
        uint32_t v1 = *(const uint32_t*)(h + (size_t)j1 * 128 + lane * 2);
        uint32_t v2 = *(const uint32_t*)(h + (size_t)j2 * 128 + lane * 2);
        uint32_t v3 = *(const uint32_t*)(h + (size_t)j3 * 128 + lane * 2);
        a0 += bflo(v0) + bflo(v1) + bflo(v2) + bflo(v3);
        a1 += bfhi(v0) + bfhi(v1) + bfhi(v2) + bfhi(v3);
    }
    for (; e < s1; ++e) {
        uint32_t v = *(const uint32_t*)(h + (size_t)ssrc[e] * 128 + lane * 2);
        a0 += bflo(v);
        a1 += bfhi(v);
    }
    float inv = 1.0f / fmaxf((float)(s1 - s0), 1.0f);
    ushort2 o;
    o.x = f2bf(a0 * inv);
    o.y = f2bf(a1 * inv);
    *(ushort2*)(out + (size_t)i * 128 + lane * 2) = o;
}

// ---------------- multi-source GEMM: out = relu(sum_i A_i @ W_i + bias) ------
__launch_bounds__(256, 2)
__global__ void gemm_k(const ushort* __restrict__ A0, const ushort* __restrict__ A1,
                       const ushort* __restrict__ A2, const ushort* __restrict__ A3,
                       const ushort* __restrict__ W0, const ushort* __restrict__ W1,
                       const ushort* __restrict__ W2, const ushort* __restrict__ W3,
                       const float* __restrict__ bias, ushort* __restrict__ out, int nsrc)
{
    __shared__ ushort a_lds[128][72];
    __shared__ ushort w_lds[128][72];
    const int tid = threadIdx.x;
    const int lane = tid & 63, wave = tid >> 6;
    const int wr = wave >> 1, wc = wave & 1;
    const size_t r0 = (size_t)blockIdx.x * 128;

    f32x4 acc[4][4];
    const f32x4 zero = {0.f, 0.f, 0.f, 0.f};
#pragma unroll
    for (int m = 0; m < 4; ++m)
#pragma unroll
        for (int n = 0; n < 4; ++n) acc[m][n] = zero;

    const ushort* As[4] = {A0, A1, A2, A3};
    const ushort* Ws[4] = {W0, W1, W2, W3};

    for (int s = 0; s < nsrc; ++s) {
        const ushort* Ap = As[s] + r0 * 128;
        const ushort* Wp = Ws[s];
        for (int k0 = 0; k0 < 128; k0 += 64) {
            __syncthreads();
#pragma unroll
            for (int j = 0; j < 4; ++j) {
                int idx = (j * 256 + tid) * 8;
                int r = idx >> 6, c = idx & 63;
                *(uint4*)&a_lds[r][c] = *(const uint4*)(Ap + r * 128 + k0 + c);
                *(uint4*)&w_lds[r][c] = *(const uint4*)(Wp + r * 128 + k0 + c);
            }
            __syncthreads();
#pragma unroll
            for (int ks = 0; ks < 64; ks += 32) {
                short8 af[4], bfr[4];
                int col = ks + ((lane >> 4) << 3);
                int ra = (wr << 6) + (lane & 15);
                int rb = (wc << 6) + (lane & 15);
#pragma unroll
                for (int m = 0; m < 4; ++m) af[m] = *(const short8*)&a_lds[ra + m * 16][col];
#pragma unroll
                for (int n = 0; n < 4; ++n) bfr[n] = *(const short8*)&w_lds[rb + n * 16][col];
#pragma unroll
                for (int m = 0; m < 4; ++m)
#pragma unroll
                    for (int n = 0; n < 4; ++n)
                        acc[m][n] = __builtin_amdgcn_mfma_f32_16x16x32_bf16(
                            af[m], bfr[n], acc[m][n], 0, 0, 0);
            }
        }
    }

    const int rbase = (wr << 6) + ((lane >> 4) << 2);
    const int cbase = (wc << 6) + (lane & 15);
#pragma unroll
    for (int m = 0; m < 4; ++m)
#pragma unroll
        for (int n = 0; n < 4; ++n) {
            int coln = cbase + n * 16;
            float bcol = bias[coln];
#pragma unroll
            for (int rg = 0; rg < 4; ++rg) {
                int row = rbase + m * 16 + rg;
                float v = acc[m][n][rg] + bcol;
                v = fmaxf(v, 0.f);
                out[(r0 + row) * 128 + coln] = f2bf(v);
            }
        }
}

// ---------------- pooling gate: gate[i] = h_p[i]·Wg + bg; segment max --------
__global__ void gate_k(const ushort* __restrict__ hp, const float* __restrict__ Wg,
                       const float* __restrict__ bg, const int* __restrict__ batch,
                       float* __restrict__ gate, unsigned* __restrict__ mbuf)
{
    int lane = threadIdx.x & 63;
    int wave = threadIdx.x >> 6;
    int i = blockIdx.x * 4 + wave;
    ushort2 h2 = *(const ushort2*)(hp + (size_t)i * 128 + lane * 2);
    float2 w2 = *(const float2*)(Wg + lane * 2);
    float g = bf2f(h2.x) * w2.x + bf2f(h2.y) * w2.y;
    for (int off = 32; off; off >>= 1) g += __shfl_down(g, off);
    if (lane == 0) {
        float gv = g + bg[0];
        gate[i] = gv;
        uint32_t u = __float_as_uint(gv);
        unsigned enc = (u & 0x80000000u) ? ~u : (u | 0x80000000u);
        atomicMax(&mbuf[batch[i]], enc);
    }
}

// ---------------- segment softmax + weighted sum -> emb[B,128] ---------------
__global__ void pool_k(const float* __restrict__ gate, const ushort* __restrict__ hp,
                       const int* __restrict__ batch, const unsigned* __restrict__ mbuf,
                       float* __restrict__ ew, float* __restrict__ emb)
{
    __shared__ float red[256];
    __shared__ int sb[2];
    __shared__ float sden;
    int b = blockIdx.x, t = threadIdx.x;
    if (t == 0) {
        int lo = 0, hi = NP;
        while (lo < hi) { int mid = (lo + hi) >> 1; if (batch[mid] < b) lo = mid + 1; else hi = mid; }
        sb[0] = lo;
        lo = 0; hi = NP;
        while (lo < hi) { int mid = (lo + hi) >> 1; if (batch[mid] < b + 1) lo = mid + 1; else hi = mid; }
        sb[1] = lo;
    }
    __syncthreads();
    int s = sb[0], e = sb[1];
    unsigned enc = mbuf[b];
    uint32_t mu = (enc & 0x80000000u) ? (enc & 0x7FFFFFFFu) : ~enc;
    float m = __uint_as_float(mu);

    float loc = 0.f;
    for (int i = s + t; i < e; i += 256) {
        float w = expf(gate[i] - m);
        ew[i] = w;
        loc += w;
    }
    red[t] = loc; __syncthreads();
    for (int o = 128; o; o >>= 1) { if (t < o) red[t] += red[t + o]; __syncthreads(); }
    if (t == 0) sden = red[0];
    __syncthreads();
    float inv = (e > s) ? 1.0f / sden : 0.f;

    int c = t & 127, half = t >> 7;
    float acc = 0.f;
    for (int i = s + half; i < e; i += 2) acc += ew[i] * bf2f(hp[(size_t)i * 128 + c]);
    __syncthreads();
    red[t] = acc; __syncthreads();
    if (t < 128) emb[b * 128 + c] = (red[c] + red[c + 128]) * inv;
}

// ---------------- actor/critic heads ----------------------------------------
__global__ void heads_k(const float* __restrict__ emb,
                        const float* __restrict__ Wa1, const float* __restrict__ ba1,
                        const float* __restrict__ Wa2, const float* __restrict__ ba2,
                        const float* __restrict__ Wc1, const float* __restrict__ bc1,
                        const float* __restrict__ Wc2, const float* __restrict__ bc2,
                        float* __restrict__ outL, float* __restrict__ outV)
{
    __shared__ float er[128], ha[128], hc[128], red[128];
    int b = blockIdx.x, t = threadIdx.x;
    if (t < 128) er[t] = emb[b * 128 + t];
    __syncthreads();
    if (t < 128) {
        float a = ba1[t];
        for (int k = 0; k < 128; ++k) a += er[k] * Wa1[k * 128 + t];
        ha[t] = fmaxf(a, 0.f);
    } else {
        int c = t - 128;
        float a = bc1[c];
        for (int k = 0; k < 128; ++k) a += er[k] * Wc1[k * 128 + c];
        hc[c] = fmaxf(a, 0.f);
    }
    __syncthreads();
    {
        float a = ba2[t];
        for (int k = 0; k < 128; ++k) a += ha[k] * Wa2[k * 256 + t];
        outL[b * 256 + t] = a;
    }
    if (t < 128) red[t] = hc[t] * Wc2[t];
    __syncthreads();
    for (int o = 64; o; o >>= 1) { if (t < o) red[t] += red[t + o]; __syncthreads(); }
    if (t == 0) outV[b] = red[0] + bc2[0];
}

// ============================================================================
extern "C" void kernel_launch(void* const* d_in, const int* in_sizes, int n_in,
                              void* d_out, int out_size, void* d_ws, size_t ws_size,
                              hipStream_t stream)
{
    const float* x_phys = (const float*)d_in[0];
    const float* x_log  = (const float*)d_in[1];
    const float* x_gate = (const float*)d_in[2];
    const int*   batch  = (const int*)d_in[3];
    const int* intra_s = (const int*)d_in[4];  const int* intra_d = (const int*)d_in[5];
    const int* inter_s = (const int*)d_in[6];  const int* inter_d = (const int*)d_in[7];
    const int* map_s   = (const int*)d_in[8];  const int* map_d   = (const int*)d_in[9];
    const int* part_s  = (const int*)d_in[10]; const int* part_d  = (const int*)d_in[11];
    const int* dep_s   = (const int*)d_in[12]; const int* dep_d   = (const int*)d_in[13];
    const int E_INTRA = in_sizes[4], E_INTER = in_sizes[6], E_MAP = in_sizes[8],
              E_PART = in_sizes[10], E_DEP = in_sizes[12];

    const float* W_phys = (const float*)d_in[14]; const float* b_phys = (const float*)d_in[15];
    const float* W_log  = (const float*)d_in[16]; const float* b_log  = (const float*)d_in[17];
    const float* W_gate = (const float*)d_in[18]; const float* b_gate = (const float*)d_in[19];
    const float* Wl1 = (const float*)d_in[20]; const float* bl1 = (const float*)d_in[21];
    const float* Wr1 = (const float*)d_in[22];
    const float* Wl2 = (const float*)d_in[23]; const float* bl2 = (const float*)d_in[24];
    const float* Wr2 = (const float*)d_in[25];
    const float* Wg  = (const float*)d_in[26]; const float* bg  = (const float*)d_in[27];
    const float* Wa1 = (const float*)d_in[28]; const float* ba1 = (const float*)d_in[29];
    const float* Wa2 = (const float*)d_in[30]; const float* ba2 = (const float*)d_in[31];
    const float* Wc1 = (const float*)d_in[32]; const float* bc1 = (const float*)d_in[33];
    const float* Wc2 = (const float*)d_in[34]; const float* bc2 = (const float*)d_in[35];

    float* outL = (float*)d_out;
    float* outV = outL + NBAT * AD;

    // ---- carve workspace ----
    char* wsp = (char*)d_ws;
    size_t off = 0;
    auto alloc = [&](size_t sz) -> void* {
        void* p = wsp + off;
        off = (off + sz + 255) & ~(size_t)255;
        return p;
    };
    ushort* hp    = (ushort*)alloc((size_t)NP * 128 * 2);
    ushort* hl    = (ushort*)alloc((size_t)NL * 128 * 2);
    ushort* hg    = (ushort*)alloc((size_t)NG * 128 * 2);
    ushort* aggbA = (ushort*)alloc((size_t)NP * 128 * 2);  // intra mean
    ushort* aggbB = (ushort*)alloc((size_t)NP * 128 * 2);  // inter mean
    ushort* Mmap  = (ushort*)alloc((size_t)NP * 128 * 2);  // mean(h_l) over map
    ushort* aggbD = (ushort*)alloc((size_t)NG * 128 * 2);  // dep mean
    ushort* Mpart = (ushort*)alloc((size_t)NG * 128 * 2);  // mean(h_l) over part

    // CSR structures (built once, reused both layers)
    int* hist = (int*)alloc((size_t)(3 * NP + 2 * NG) * 4);   // contiguous for one memset
    int* hist_intra = hist;
    int* hist_inter = hist + NP;
    int* hist_map   = hist + 2 * NP;
    int* hist_part  = hist + 3 * NP;
    int* hist_dep   = hist + 3 * NP + NG;
    int* rp_intra = (int*)alloc((size_t)(NP + 1) * 4);
    int* rp_inter = (int*)alloc((size_t)(NP + 1) * 4);
    int* rp_map   = (int*)alloc((size_t)(NP + 1) * 4);
    int* rp_part  = (int*)alloc((size_t)(NG + 1) * 4);
    int* rp_dep   = (int*)alloc((size_t)(NG + 1) * 4);
    int* fl_intra = (int*)alloc((size_t)NP * 4);
    int* fl_inter = (int*)alloc((size_t)NP * 4);
    int* fl_map   = (int*)alloc((size_t)NP * 4);
    int* fl_part  = (int*)alloc((size_t)NG * 4);
    int* fl_dep   = (int*)alloc((size_t)NG * 4);
    int* ss_intra = (int*)alloc((size_t)E_INTRA * 4);
    int* ss_inter = (int*)alloc((size_t)E_INTER * 4);
    int* ss_map   = (int*)alloc((size_t)E_MAP * 4);
    int* ss_part  = (int*)alloc((size_t)E_PART * 4);
    int* ss_dep   = (int*)alloc((size_t)E_DEP * 4);

    float*    gate = (float*)alloc((size_t)NP * 4);
    float*    ew   = (float*)alloc((size_t)NP * 4);
    unsigned* mbuf = (unsigned*)alloc(NBAT * 4);
    float*    emb  = (float*)alloc(NBAT * 128 * 4);
    ushort*   wlt  = (ushort*)alloc((size_t)2 * 7 * 16384 * 2);
    float*    bsum = (float*)alloc(2 * 256 * 4);
    (void)ws_size; (void)out_size; (void)n_in;

    // ---- weight prep + encoders ----
    prep_w<<<15, 256, 0, stream>>>(Wl1, Wr1, bl1, Wl2, Wr2, bl2, wlt, bsum);
    encode_k<<<NP / 2, 256, 0, stream>>>(x_phys, W_phys, b_phys, hp, 5);
    encode_k<<<NL / 2, 256, 0, stream>>>(x_log, W_log, b_log, hl, 1);
    encode_k<<<NG / 2, 256, 0, stream>>>(x_gate, W_gate, b_gate, hg, 2);

    // ---- CSR build (once; reused across both layers) ----
    hipMemsetAsync(hist, 0, (size_t)(3 * NP + 2 * NG) * 4, stream);
    hist_k<<<(E_INTRA + 255) / 256, 256, 0, stream>>>(intra_d, hist_intra, E_INTRA);
    hist_k<<<(E_INTER + 255) / 256, 256, 0, stream>>>(inter_d, hist_inter, E_INTER);
    hist_k<<<(E_MAP + 255) / 256, 256, 0, stream>>>(map_d, hist_map, E_MAP);
    hist_k<<<(E_PART + 255) / 256, 256, 0, stream>>>(part_d, hist_part, E_PART);
    hist_k<<<(E_DEP + 255) / 256, 256, 0, stream>>>(dep_d, hist_dep, E_DEP);
    scan_k<<<1, 1024, 0, stream>>>(hist_intra, rp_intra, fl_intra, NP);
    scan_k<<<1, 1024, 0, stream>>>(hist_inter, rp_inter, fl_inter, NP);
    scan_k<<<1, 1024, 0, stream>>>(hist_map,   rp_map,   fl_map,   NP);
    scan_k<<<1, 1024, 0, stream>>>(hist_part,  rp_part,  fl_part,  NG);
    scan_k<<<1, 1024, 0, stream>>>(hist_dep,   rp_dep,   fl_dep,   NG);
    fill_k<<<(E_INTRA + 255) / 256, 256, 0, stream>>>(intra_s, intra_d, fl_intra, ss_intra, E_INTRA);
    fill_k<<<(E_INTER + 255) / 256, 256, 0, stream>>>(inter_s, inter_d, fl_inter, ss_inter, E_INTER);
    fill_k<<<(E_MAP + 255) / 256, 256, 0, stream>>>(map_s, map_d, fl_map, ss_map, E_MAP);
    fill_k<<<(E_PART + 255) / 256, 256, 0, stream>>>(part_s, part_d, fl_part, ss_part, E_PART);
    fill_k<<<(E_DEP + 255) / 256, 256, 0, stream>>>(dep_s, dep_d, fl_dep, ss_dep, E_DEP);

    // ---- static aggregations from h_l (reused by both layers) ----
    gather_mean_k<<<NP / 4, 256, 0, stream>>>(hl, rp_map, ss_map, Mmap, NP);
    gather_mean_k<<<NG / 4, 256, 0, stream>>>(hl, rp_part, ss_part, Mpart, NG);

    // ---- two hetero layers ----
    for (int l = 0; l < 2; ++l) {
        const ushort* wl = wlt + (size_t)l * 7 * 16384;
        const float* blp = bsum + l * 256;
        const float* blg = blp + 128;

        gather_mean_k<<<NP / 4, 256, 0, stream>>>(hp, rp_intra, ss_intra, aggbA, NP);
        gather_mean_k<<<NP / 4, 256, 0, stream>>>(hp, rp_inter, ss_inter, aggbB, NP);
        gather_mean_k<<<NG / 4, 256, 0, stream>>>(hg, rp_dep, ss_dep, aggbD, NG);

        // out_p = relu(meanI@Wl0 + meanT@Wl1 + Mmap@Wl2 + hp@(Wr0+Wr1+Wr2) + blp)
        gemm_k<<<NP / 128, 256, 0, stream>>>(aggbA, aggbB, Mmap, hp,
                                             wl + 0 * 16384, wl + 1 * 16384,
                                             wl + 2 * 16384, wl + 5 * 16384,
                                             blp, hp, 4);
        // out_g = relu(Mpart@Wl3 + meanD@Wl4 + hg@(Wr3+Wr4) + blg)
        gemm_k<<<NG / 128, 256, 0, stream>>>(Mpart, aggbD, hg, nullptr,
                                             wl + 3 * 16384, wl + 4 * 16384,
                                             wl + 6 * 16384, nullptr,
                                             blg, hg, 3);
    }

    // ---- attentional pooling + heads ----
    hipMemsetAsync(mbuf, 0, NBAT * 4, stream);
    gate_k<<<NP / 4, 256, 0, stream>>>(hp, Wg, bg, batch, gate, mbuf);
    pool_k<<<NBAT, 256, 0, stream>>>(gate, hp, batch, mbuf, ew, emb);
    heads_k<<<NBAT, 256, 0, stream>>>(emb, Wa1, ba1, Wa2, ba2, Wc1, bc1, Wc2, bc2, outL, outV);
}

// Round 5
// 1057.915 us; speedup vs baseline: 7.1500x; 1.9461x over previous
//
#include <hip/hip_runtime.h>
#include <stdint.h>

#define H    128
#define NBAT 128
#define AD   256
#define NP   65536
#define NL   32768
#define NG   131072

typedef __attribute__((ext_vector_type(8))) short short8;
typedef __attribute__((ext_vector_type(4))) float f32x4;

__device__ __forceinline__ ushort f2bf(float f) {
    uint32_t u = __float_as_uint(f);
    u += 0x7FFFu + ((u >> 16) & 1u);
    return (ushort)(u >> 16);
}
__device__ __forceinline__ float bf2f(ushort h) {
    return __uint_as_float(((uint32_t)h) << 16);
}
__device__ __forceinline__ float bflo(uint32_t v) { return __uint_as_float(v << 16); }
__device__ __forceinline__ float bfhi(uint32_t v) { return __uint_as_float(v & 0xFFFF0000u); }

// ---------------- weight prep: bf16 transposed [n][k] copies + sums ----------
__global__ void prep_w(const float* __restrict__ Wl1, const float* __restrict__ Wr1,
                       const float* __restrict__ bl1,
                       const float* __restrict__ Wl2, const float* __restrict__ Wr2,
                       const float* __restrict__ bl2,
                       ushort* __restrict__ wlt,  // [2][7][128*128] (n-major)
                       float* __restrict__ bsum)  // [2][256]
{
    int m = blockIdx.x;
    if (m < 14) {
        int l = m / 7, r = m % 7;
        const float* Wl = l ? Wl2 : Wl1;
        const float* Wr = l ? Wr2 : Wr1;
        ushort* dst = wlt + (size_t)m * 16384;
        for (int it = 0; it < 64; ++it) {
            int idx = it * 256 + threadIdx.x;
            int k = idx >> 7, n = idx & 127;
            float v;
            if (r < 5)       v = Wl[r * 16384 + k * 128 + n];
            else if (r == 5) v = Wr[0 * 16384 + k * 128 + n] + Wr[1 * 16384 + k * 128 + n]
                               + Wr[2 * 16384 + k * 128 + n];
            else             v = Wr[3 * 16384 + k * 128 + n] + Wr[4 * 16384 + k * 128 + n];
            dst[n * 128 + k] = f2bf(v);
        }
    } else {
        int t = threadIdx.x;
        if (t < 128) {
            bsum[0 * 256 + t]       = bl1[0 * 128 + t] + bl1[1 * 128 + t] + bl1[2 * 128 + t];
            bsum[0 * 256 + 128 + t] = bl1[3 * 128 + t] + bl1[4 * 128 + t];
            bsum[1 * 256 + t]       = bl2[0 * 128 + t] + bl2[1 * 128 + t] + bl2[2 * 128 + t];
            bsum[1 * 256 + 128 + t] = bl2[3 * 128 + t] + bl2[4 * 128 + t];
        }
    }
}

// ---------------- encoders: h = relu(x @ W + b) -> bf16 ----------------------
__global__ void encode_k(const float* __restrict__ x, const float* __restrict__ W,
                         const float* __restrict__ b, ushort* __restrict__ out, int K)
{
    int t = threadIdx.x;
    int i = blockIdx.x * 2 + (t >> 7);
    int c = t & 127;
    float acc = b[c];
    for (int k = 0; k < K; ++k) acc += x[(size_t)i * K + k] * W[k * 128 + c];
    out[(size_t)i * 128 + c] = f2bf(fmaxf(acc, 0.f));
}

// ---------------- CSR build: histogram -> scan -> fill -----------------------
__global__ void hist_k(const int* __restrict__ dst, int* __restrict__ hist, int E)
{
    int e = blockIdx.x * 256 + threadIdx.x;
    if (e < E) atomicAdd(&hist[dst[e]], 1);
}

// 5 independent single-block exclusive scans in ONE launch (grid = 5).
// block b scans hist type b of length N_b into rowptr/fill.
__global__ void scan5_k(const int* __restrict__ h_intra, const int* __restrict__ h_inter,
                        const int* __restrict__ h_map,   const int* __restrict__ h_part,
                        const int* __restrict__ h_dep,
                        int* __restrict__ rp_intra, int* __restrict__ rp_inter,
                        int* __restrict__ rp_map,   int* __restrict__ rp_part,
                        int* __restrict__ rp_dep,
                        int* __restrict__ fl_intra, int* __restrict__ fl_inter,
                        int* __restrict__ fl_map,   int* __restrict__ fl_part,
                        int* __restrict__ fl_dep)
{
    __shared__ int lds[1024];
    const int* hist; int* rowptr; int* fill; int N;
    switch (blockIdx.x) {
        case 0: hist = h_intra; rowptr = rp_intra; fill = fl_intra; N = NP; break;
        case 1: hist = h_inter; rowptr = rp_inter; fill = fl_inter; N = NP; break;
        case 2: hist = h_map;   rowptr = rp_map;   fill = fl_map;   N = NP; break;
        case 3: hist = h_part;  rowptr = rp_part;  fill = fl_part;  N = NG; break;
        default: hist = h_dep;  rowptr = rp_dep;   fill = fl_dep;   N = NG; break;
    }
    int t = threadIdx.x;
    int C = N >> 10;
    int base = t * C;
    int s = 0;
    for (int j = 0; j < C; ++j) s += hist[base + j];
    lds[t] = s;
    __syncthreads();
    for (int d = 1; d < 1024; d <<= 1) {
        int v = (t >= d) ? lds[t - d] : 0;
        __syncthreads();
        lds[t] += v;
        __syncthreads();
    }
    int run = (t == 0) ? 0 : lds[t - 1];
    for (int j = 0; j < C; ++j) {
        int hv = hist[base + j];
        rowptr[base + j] = run;
        fill[base + j] = run;
        run += hv;
    }
    if (t == 1023) rowptr[N] = run;
}

__global__ void fill_k(const int* __restrict__ src, const int* __restrict__ dst,
                       int* __restrict__ fill, int* __restrict__ ssrc, int E)
{
    int e = blockIdx.x * 256 + threadIdx.x;
    if (e < E) {
        int p = atomicAdd(&fill[dst[e]], 1);
        ssrc[p] = src[e];
    }
}

// ---------------- gather-mean: one wave per destination node -----------------
__global__ void gather_mean_k(const ushort* __restrict__ h, const int* __restrict__ rowptr,
                              const int* __restrict__ ssrc, ushort* __restrict__ out, int N)
{
    int i = blockIdx.x * 4 + (threadIdx.x >> 6);
    int lane = threadIdx.x & 63;
    int s0 = rowptr[i], s1 = rowptr[i + 1];
    float a0 = 0.f, a1 = 0.f;
    int e = s0;
    for (; e + 4 <= s1; e += 4) {
        int j0 = ssrc[e], j1 = ssrc[e + 1], j2 = ssrc[e + 2], j3 = ssrc[e + 3];
        uint32_t v0 = *(const uint32_t*)(h + (size_t)j0 * 128 + lane * 2);
        uint32_t v1 = *(const uint32_t*)(h + (size_t)j1 * 128 + lane * 2);
        uint32_t v2 = *(const uint32_t*)(h + (size_t)j2 * 128 + lane * 2);
        uint32_t v3 = *(const uint32_t*)(h + (size_t)j3 * 128 + lane * 2);
        a0 += bflo(v0) + bflo(v1) + bflo(v2) + bflo(v3);
        a1 += bfhi(v0) + bfhi(v1) + bfhi(v2) + bfhi(v3);
    }
    for (; e < s1; ++e) {
        uint32_t v = *(const uint32_t*)(h + (size_t)ssrc[e] * 128 + lane * 2);
        a0 += bflo(v);
        a1 += bfhi(v);
    }
    float inv = 1.0f / fmaxf((float)(s1 - s0), 1.0f);
    ushort2 o;
    o.x = f2bf(a0 * inv);
    o.y = f2bf(a1 * inv);
    *(ushort2*)(out + (size_t)i * 128 + lane * 2) = o;
}

// ---------------- multi-source GEMM: out = relu(sum_i A_i @ W_i + bias) ------
__launch_bounds__(256, 2)
__global__ void gemm_k(const ushort* __restrict__ A0, const ushort* __restrict__ A1,
                       const ushort* __restrict__ A2, const ushort* __restrict__ A3,
                       const ushort* __restrict__ W0, const ushort* __restrict__ W1,
                       const ushort* __restrict__ W2, const ushort* __restrict__ W3,
                       const float* __restrict__ bias, ushort* __restrict__ out, int nsrc)
{
    __shared__ ushort a_lds[128][72];
    __shared__ ushort w_lds[128][72];
    const int tid = threadIdx.x;
    const int lane = tid & 63, wave = tid >> 6;
    const int wr = wave >> 1, wc = wave & 1;
    const size_t r0 = (size_t)blockIdx.x * 128;

    f32x4 acc[4][4];
    const f32x4 zero = {0.f, 0.f, 0.f, 0.f};
#pragma unroll
    for (int m = 0; m < 4; ++m)
#pragma unroll
        for (int n = 0; n < 4; ++n) acc[m][n] = zero;

    const ushort* As[4] = {A0, A1, A2, A3};
    const ushort* Ws[4] = {W0, W1, W2, W3};

    for (int s = 0; s < nsrc; ++s) {
        const ushort* Ap = As[s] + r0 * 128;
        const ushort* Wp = Ws[s];
        for (int k0 = 0; k0 < 128; k0 += 64) {
            __syncthreads();
#pragma unroll
            for (int j = 0; j < 4; ++j) {
                int idx = (j * 256 + tid) * 8;
                int r = idx >> 6, c = idx & 63;
                *(uint4*)&a_lds[r][c] = *(const uint4*)(Ap + r * 128 + k0 + c);
                *(uint4*)&w_lds[r][c] = *(const uint4*)(Wp + r * 128 + k0 + c);
            }
            __syncthreads();
#pragma unroll
            for (int ks = 0; ks < 64; ks += 32) {
                short8 af[4], bfr[4];
                int col = ks + ((lane >> 4) << 3);
                int ra = (wr << 6) + (lane & 15);
                int rb = (wc << 6) + (lane & 15);
#pragma unroll
                for (int m = 0; m < 4; ++m) af[m] = *(const short8*)&a_lds[ra + m * 16][col];
#pragma unroll
                for (int n = 0; n < 4; ++n) bfr[n] = *(const short8*)&w_lds[rb + n * 16][col];
#pragma unroll
                for (int m = 0; m < 4; ++m)
#pragma unroll
                    for (int n = 0; n < 4; ++n)
                        acc[m][n] = __builtin_amdgcn_mfma_f32_16x16x32_bf16(
                            af[m], bfr[n], acc[m][n], 0, 0, 0);
            }
        }
    }

    const int rbase = (wr << 6) + ((lane >> 4) << 2);
    const int cbase = (wc << 6) + (lane & 15);
#pragma unroll
    for (int m = 0; m < 4; ++m)
#pragma unroll
        for (int n = 0; n < 4; ++n) {
            int coln = cbase + n * 16;
            float bcol = bias[coln];
#pragma unroll
            for (int rg = 0; rg < 4; ++rg) {
                int row = rbase + m * 16 + rg;
                float v = acc[m][n][rg] + bcol;
                v = fmaxf(v, 0.f);
                out[(r0 + row) * 128 + coln] = f2bf(v);
            }
        }
}

// ---------------- pooling gate: gate[i] = h_p[i]·Wg + bg ---------------------
// (no atomicMax: segment max is computed inside pool_k, which scans the
//  segment anyway — the old 65536-atomics-to-8-cache-lines cost 342 us)
__global__ void gate_k(const ushort* __restrict__ hp, const float* __restrict__ Wg,
                       const float* __restrict__ bg, float* __restrict__ gate)
{
    int lane = threadIdx.x & 63;
    int wave = threadIdx.x >> 6;
    int i = blockIdx.x * 4 + wave;
    ushort2 h2 = *(const ushort2*)(hp + (size_t)i * 128 + lane * 2);
    float2 w2 = *(const float2*)(Wg + lane * 2);
    float g = bf2f(h2.x) * w2.x + bf2f(h2.y) * w2.y;
    for (int off = 32; off; off >>= 1) g += __shfl_down(g, off);
    if (lane == 0) gate[i] = g + bg[0];
}

// ---------------- segment softmax + weighted sum -> emb[B,128] ---------------
__global__ void pool_k(const float* __restrict__ gate, const ushort* __restrict__ hp,
                       const int* __restrict__ batch,
                       float* __restrict__ ew, float* __restrict__ emb)
{
    __shared__ float red[256];
    __shared__ int sb[2];
    __shared__ float sm, sden;
    int b = blockIdx.x, t = threadIdx.x;
    if (t < 2) {
        int target = b + t;
        int lo = 0, hi = NP;
        while (lo < hi) { int mid = (lo + hi) >> 1; if (batch[mid] < target) lo = mid + 1; else hi = mid; }
        sb[t] = lo;
    }
    __syncthreads();
    int s = sb[0], e = sb[1];

    // segment max
    float lm = -3.4e38f;
    for (int i = s + t; i < e; i += 256) lm = fmaxf(lm, gate[i]);
    red[t] = lm; __syncthreads();
    for (int o = 128; o; o >>= 1) { if (t < o) red[t] = fmaxf(red[t], red[t + o]); __syncthreads(); }
    if (t == 0) sm = red[0];
    __syncthreads();
    float m = sm;

    // exp + denom
    float loc = 0.f;
    for (int i = s + t; i < e; i += 256) {
        float w = expf(gate[i] - m);
        ew[i] = w;
        loc += w;
    }
    red[t] = loc; __syncthreads();
    for (int o = 128; o; o >>= 1) { if (t < o) red[t] += red[t + o]; __syncthreads(); }
    if (t == 0) sden = red[0];
    __syncthreads();
    float inv = (e > s) ? 1.0f / sden : 0.f;

    // weighted sum
    int c = t & 127, half = t >> 7;
    float acc = 0.f;
    for (int i = s + half; i < e; i += 2) acc += ew[i] * bf2f(hp[(size_t)i * 128 + c]);
    __syncthreads();
    red[t] = acc; __syncthreads();
    if (t < 128) emb[b * 128 + c] = (red[c] + red[c + 128]) * inv;
}

// ---------------- actor/critic heads ----------------------------------------
__global__ void heads_k(const float* __restrict__ emb,
                        const float* __restrict__ Wa1, const float* __restrict__ ba1,
                        const float* __restrict__ Wa2, const float* __restrict__ ba2,
                        const float* __restrict__ Wc1, const float* __restrict__ bc1,
                        const float* __restrict__ Wc2, const float* __restrict__ bc2,
                        float* __restrict__ outL, float* __restrict__ outV)
{
    __shared__ float er[128], ha[128], hc[128], red[128];
    int b = blockIdx.x, t = threadIdx.x;
    if (t < 128) er[t] = emb[b * 128 + t];
    __syncthreads();
    if (t < 128) {
        float a = ba1[t];
        for (int k = 0; k < 128; ++k) a += er[k] * Wa1[k * 128 + t];
        ha[t] = fmaxf(a, 0.f);
    } else {
        int c = t - 128;
        float a = bc1[c];
        for (int k = 0; k < 128; ++k) a += er[k] * Wc1[k * 128 + c];
        hc[c] = fmaxf(a, 0.f);
    }
    __syncthreads();
    {
        float a = ba2[t];
        for (int k = 0; k < 128; ++k) a += ha[k] * Wa2[k * 256 + t];
        outL[b * 256 + t] = a;
    }
    if (t < 128) red[t] = hc[t] * Wc2[t];
    __syncthreads();
    for (int o = 64; o; o >>= 1) { if (t < o) red[t] += red[t + o]; __syncthreads(); }
    if (t == 0) outV[b] = red[0] + bc2[0];
}

// ============================================================================
extern "C" void kernel_launch(void* const* d_in, const int* in_sizes, int n_in,
                              void* d_out, int out_size, void* d_ws, size_t ws_size,
                              hipStream_t stream)
{
    const float* x_phys = (const float*)d_in[0];
    const float* x_log  = (const float*)d_in[1];
    const float* x_gate = (const float*)d_in[2];
    const int*   batch  = (const int*)d_in[3];
    const int* intra_s = (const int*)d_in[4];  const int* intra_d = (const int*)d_in[5];
    const int* inter_s = (const int*)d_in[6];  const int* inter_d = (const int*)d_in[7];
    const int* map_s   = (const int*)d_in[8];  const int* map_d   = (const int*)d_in[9];
    const int* part_s  = (const int*)d_in[10]; const int* part_d  = (const int*)d_in[11];
    const int* dep_s   = (const int*)d_in[12]; const int* dep_d   = (const int*)d_in[13];
    const int E_INTRA = in_sizes[4], E_INTER = in_sizes[6], E_MAP = in_sizes[8],
              E_PART = in_sizes[10], E_DEP = in_sizes[12];

    const float* W_phys = (const float*)d_in[14]; const float* b_phys = (const float*)d_in[15];
    const float* W_log  = (const float*)d_in[16]; const float* b_log  = (const float*)d_in[17];
    const float* W_gate = (const float*)d_in[18]; const float* b_gate = (const float*)d_in[19];
    const float* Wl1 = (const float*)d_in[20]; const float* bl1 = (const float*)d_in[21];
    const float* Wr1 = (const float*)d_in[22];
    const float* Wl2 = (const float*)d_in[23]; const float* bl2 = (const float*)d_in[24];
    const float* Wr2 = (const float*)d_in[25];
    const float* Wg  = (const float*)d_in[26]; const float* bg  = (const float*)d_in[27];
    const float* Wa1 = (const float*)d_in[28]; const float* ba1 = (const float*)d_in[29];
    const float* Wa2 = (const float*)d_in[30]; const float* ba2 = (const float*)d_in[31];
    const float* Wc1 = (const float*)d_in[32]; const float* bc1 = (const float*)d_in[33];
    const float* Wc2 = (const float*)d_in[34]; const float* bc2 = (const float*)d_in[35];

    float* outL = (float*)d_out;
    float* outV = outL + NBAT * AD;

    // ---- carve workspace ----
    char* wsp = (char*)d_ws;
    size_t off = 0;
    auto alloc = [&](size_t sz) -> void* {
        void* p = wsp + off;
        off = (off + sz + 255) & ~(size_t)255;
        return p;
    };
    ushort* hp    = (ushort*)alloc((size_t)NP * 128 * 2);
    ushort* hl    = (ushort*)alloc((size_t)NL * 128 * 2);
    ushort* hg    = (ushort*)alloc((size_t)NG * 128 * 2);
    ushort* aggbA = (ushort*)alloc((size_t)NP * 128 * 2);  // intra mean
    ushort* aggbB = (ushort*)alloc((size_t)NP * 128 * 2);  // inter mean
    ushort* Mmap  = (ushort*)alloc((size_t)NP * 128 * 2);  // mean(h_l) over map
    ushort* aggbD = (ushort*)alloc((size_t)NG * 128 * 2);  // dep mean
    ushort* Mpart = (ushort*)alloc((size_t)NG * 128 * 2);  // mean(h_l) over part

    // CSR structures (built once, reused both layers)
    int* hist = (int*)alloc((size_t)(3 * NP + 2 * NG) * 4);   // contiguous for one memset
    int* hist_intra = hist;
    int* hist_inter = hist + NP;
    int* hist_map   = hist + 2 * NP;
    int* hist_part  = hist + 3 * NP;
    int* hist_dep   = hist + 3 * NP + NG;
    int* rp_intra = (int*)alloc((size_t)(NP + 1) * 4);
    int* rp_inter = (int*)alloc((size_t)(NP + 1) * 4);
    int* rp_map   = (int*)alloc((size_t)(NP + 1) * 4);
    int* rp_part  = (int*)alloc((size_t)(NG + 1) * 4);
    int* rp_dep   = (int*)alloc((size_t)(NG + 1) * 4);
    int* fl_intra = (int*)alloc((size_t)NP * 4);
    int* fl_inter = (int*)alloc((size_t)NP * 4);
    int* fl_map   = (int*)alloc((size_t)NP * 4);
    int* fl_part  = (int*)alloc((size_t)NG * 4);
    int* fl_dep   = (int*)alloc((size_t)NG * 4);
    int* ss_intra = (int*)alloc((size_t)E_INTRA * 4);
    int* ss_inter = (int*)alloc((size_t)E_INTER * 4);
    int* ss_map   = (int*)alloc((size_t)E_MAP * 4);
    int* ss_part  = (int*)alloc((size_t)E_PART * 4);
    int* ss_dep   = (int*)alloc((size_t)E_DEP * 4);

    float*    gate = (float*)alloc((size_t)NP * 4);
    float*    ew   = (float*)alloc((size_t)NP * 4);
    float*    emb  = (float*)alloc(NBAT * 128 * 4);
    ushort*   wlt  = (ushort*)alloc((size_t)2 * 7 * 16384 * 2);
    float*    bsum = (float*)alloc(2 * 256 * 4);
    (void)ws_size; (void)out_size; (void)n_in;

    // ---- weight prep + encoders ----
    prep_w<<<15, 256, 0, stream>>>(Wl1, Wr1, bl1, Wl2, Wr2, bl2, wlt, bsum);
    encode_k<<<NP / 2, 256, 0, stream>>>(x_phys, W_phys, b_phys, hp, 5);
    encode_k<<<NL / 2, 256, 0, stream>>>(x_log, W_log, b_log, hl, 1);
    encode_k<<<NG / 2, 256, 0, stream>>>(x_gate, W_gate, b_gate, hg, 2);

    // ---- CSR build (once; reused across both layers) ----
    hipMemsetAsync(hist, 0, (size_t)(3 * NP + 2 * NG) * 4, stream);
    hist_k<<<(E_INTRA + 255) / 256, 256, 0, stream>>>(intra_d, hist_intra, E_INTRA);
    hist_k<<<(E_INTER + 255) / 256, 256, 0, stream>>>(inter_d, hist_inter, E_INTER);
    hist_k<<<(E_MAP + 255) / 256, 256, 0, stream>>>(map_d, hist_map, E_MAP);
    hist_k<<<(E_PART + 255) / 256, 256, 0, stream>>>(part_d, hist_part, E_PART);
    hist_k<<<(E_DEP + 255) / 256, 256, 0, stream>>>(dep_d, hist_dep, E_DEP);
    scan5_k<<<5, 1024, 0, stream>>>(hist_intra, hist_inter, hist_map, hist_part, hist_dep,
                                    rp_intra, rp_inter, rp_map, rp_part, rp_dep,
                                    fl_intra, fl_inter, fl_map, fl_part, fl_dep);
    fill_k<<<(E_INTRA + 255) / 256, 256, 0, stream>>>(intra_s, intra_d, fl_intra, ss_intra, E_INTRA);
    fill_k<<<(E_INTER + 255) / 256, 256, 0, stream>>>(inter_s, inter_d, fl_inter, ss_inter, E_INTER);
    fill_k<<<(E_MAP + 255) / 256, 256, 0, stream>>>(map_s, map_d, fl_map, ss_map, E_MAP);
    fill_k<<<(E_PART + 255) / 256, 256, 0, stream>>>(part_s, part_d, fl_part, ss_part, E_PART);
    fill_k<<<(E_DEP + 255) / 256, 256, 0, stream>>>(dep_s, dep_d, fl_dep, ss_dep, E_DEP);

    // ---- static aggregations from h_l (reused by both layers) ----
    gather_mean_k<<<NP / 4, 256, 0, stream>>>(hl, rp_map, ss_map, Mmap, NP);
    gather_mean_k<<<NG / 4, 256, 0, stream>>>(hl, rp_part, ss_part, Mpart, NG);

    // ---- two hetero layers ----
    for (int l = 0; l < 2; ++l) {
        const ushort* wl = wlt + (size_t)l * 7 * 16384;
        const float* blp = bsum + l * 256;
        const float* blg = blp + 128;

        gather_mean_k<<<NP / 4, 256, 0, stream>>>(hp, rp_intra, ss_intra, aggbA, NP);
        gather_mean_k<<<NP / 4, 256, 0, stream>>>(hp, rp_inter, ss_inter, aggbB, NP);
        gather_mean_k<<<NG / 4, 256, 0, stream>>>(hg, rp_dep, ss_dep, aggbD, NG);

        // out_p = relu(meanI@Wl0 + meanT@Wl1 + Mmap@Wl2 + hp@(Wr0+Wr1+Wr2) + blp)
        gemm_k<<<NP / 128, 256, 0, stream>>>(aggbA, aggbB, Mmap, hp,
                                             wl + 0 * 16384, wl + 1 * 16384,
                                             wl + 2 * 16384, wl + 5 * 16384,
                                             blp, hp, 4);
        // out_g = relu(Mpart@Wl3 + meanD@Wl4 + hg@(Wr3+Wr4) + blg)
        gemm_k<<<NG / 128, 256, 0, stream>>>(Mpart, aggbD, hg, nullptr,
                                             wl + 3 * 16384, wl + 4 * 16384,
                                             wl + 6 * 16384, nullptr,
                                             blg, hg, 3);
    }

    // ---- attentional pooling + heads ----
    gate_k<<<NP / 4, 256, 0, stream>>>(hp, Wg, bg, gate);
    pool_k<<<NBAT, 256, 0, stream>>>(gate, hp, batch, ew, emb);
    heads_k<<<NBAT, 256, 0, stream>>>(emb, Wa1, ba1, Wa2, ba2, Wc1, bc1, Wc2, bc2, outL, outV);
}

// Round 6
// 785.901 us; speedup vs baseline: 9.6248x; 1.3461x over previous
//
#include <hip/hip_runtime.h>
#include <stdint.h>

#define H    128
#define NBAT 128
#define AD   256
#define NP   65536
#define NL   32768
#define NG   131072
#define NTOT (3 * NP + 2 * NG)      // 458752 concatenated CSR nodes
#define SCAN_B (NTOT / 256)         // 1792 scan blocks

typedef __attribute__((ext_vector_type(8))) short short8;
typedef __attribute__((ext_vector_type(4))) float f32x4;

__device__ __forceinline__ ushort f2bf(float f) {
    uint32_t u = __float_as_uint(f);
    u += 0x7FFFu + ((u >> 16) & 1u);
    return (ushort)(u >> 16);
}
__device__ __forceinline__ float bf2f(ushort h) {
    return __uint_as_float(((uint32_t)h) << 16);
}
__device__ __forceinline__ float bflo(uint32_t v) { return __uint_as_float(v << 16); }
__device__ __forceinline__ float bfhi(uint32_t v) { return __uint_as_float(v & 0xFFFF0000u); }

// ---------------- weight prep: bf16 transposed [n][k] copies + sums ----------
__global__ void prep_w(const float* __restrict__ Wl1, const float* __restrict__ Wr1,
                       const float* __restrict__ bl1,
                       const float* __restrict__ Wl2, const float* __restrict__ Wr2,
                       const float* __restrict__ bl2,
                       ushort* __restrict__ wlt,  // [2][7][128*128] (n-major)
                       float* __restrict__ bsum)  // [2][256]
{
    int m = blockIdx.x;
    if (m < 14) {
        int l = m / 7, r = m % 7;
        const float* Wl = l ? Wl2 : Wl1;
        const float* Wr = l ? Wr2 : Wr1;
        ushort* dst = wlt + (size_t)m * 16384;
        for (int it = 0; it < 64; ++it) {
            int idx = it * 256 + threadIdx.x;
            int k = idx >> 7, n = idx & 127;
            float v;
            if (r < 5)       v = Wl[r * 16384 + k * 128 + n];
            else if (r == 5) v = Wr[0 * 16384 + k * 128 + n] + Wr[1 * 16384 + k * 128 + n]
                               + Wr[2 * 16384 + k * 128 + n];
            else             v = Wr[3 * 16384 + k * 128 + n] + Wr[4 * 16384 + k * 128 + n];
            dst[n * 128 + k] = f2bf(v);
        }
    } else {
        int t = threadIdx.x;
        if (t < 128) {
            bsum[0 * 256 + t]       = bl1[0 * 128 + t] + bl1[1 * 128 + t] + bl1[2 * 128 + t];
            bsum[0 * 256 + 128 + t] = bl1[3 * 128 + t] + bl1[4 * 128 + t];
            bsum[1 * 256 + t]       = bl2[0 * 128 + t] + bl2[1 * 128 + t] + bl2[2 * 128 + t];
            bsum[1 * 256 + 128 + t] = bl2[3 * 128 + t] + bl2[4 * 128 + t];
        }
    }
}

// ---------------- encoders: h = relu(x @ W + b) -> bf16 ----------------------
__global__ void encode_k(const float* __restrict__ x, const float* __restrict__ W,
                         const float* __restrict__ b, ushort* __restrict__ out, int K)
{
    int t = threadIdx.x;
    int i = blockIdx.x * 2 + (t >> 7);
    int c = t & 127;
    float acc = b[c];
    for (int k = 0; k < K; ++k) acc += x[(size_t)i * K + k] * W[k * 128 + c];
    out[(size_t)i * 128 + c] = f2bf(fmaxf(acc, 0.f));
}

// ---------------- CSR build: histogram -> hierarchical scan -> fill ----------
__global__ void hist_k(const int* __restrict__ dst, int* __restrict__ hist, int E)
{
    int e = blockIdx.x * 256 + threadIdx.x;
    if (e < E) atomicAdd(&hist[dst[e]], 1);
}

// A: per-block (256-elem) sums of the concatenated histogram
__global__ void scanA_k(const int* __restrict__ hist, int* __restrict__ partials)
{
    __shared__ int red[256];
    int t = threadIdx.x;
    red[t] = hist[blockIdx.x * 256 + t];
    __syncthreads();
    for (int o = 128; o; o >>= 1) { if (t < o) red[t] += red[t + o]; __syncthreads(); }
    if (t == 0) partials[blockIdx.x] = red[0];
}

// B: one block exclusive-scans the 1792 partials in place
__global__ void scanB_k(int* __restrict__ partials)
{
    __shared__ int lds[1024];
    int t = threadIdx.x;
    int v0 = (2 * t     < SCAN_B) ? partials[2 * t]     : 0;
    int v1 = (2 * t + 1 < SCAN_B) ? partials[2 * t + 1] : 0;
    lds[t] = v0 + v1;
    __syncthreads();
    for (int d = 1; d < 1024; d <<= 1) {
        int v = (t >= d) ? lds[t - d] : 0;
        __syncthreads();
        lds[t] += v;
        __syncthreads();
    }
    int base = (t == 0) ? 0 : lds[t - 1];
    if (2 * t     < SCAN_B) partials[2 * t]     = base;
    if (2 * t + 1 < SCAN_B) partials[2 * t + 1] = base + v0;
}

// C: local exclusive scan + block base -> rowptr (global offsets) + fill copy
__global__ void scanC_k(const int* __restrict__ hist, const int* __restrict__ partials,
                        int* __restrict__ rowptr, int* __restrict__ fill)
{
    __shared__ int lds[256];
    int t = threadIdx.x;
    int idx = blockIdx.x * 256 + t;
    int v = hist[idx];
    lds[t] = v;
    __syncthreads();
    for (int d = 1; d < 256; d <<= 1) {
        int x = (t >= d) ? lds[t - d] : 0;
        __syncthreads();
        lds[t] += x;
        __syncthreads();
    }
    int excl = lds[t] - v + partials[blockIdx.x];
    rowptr[idx] = excl;
    fill[idx] = excl;
    if (idx == NTOT - 1) rowptr[NTOT] = excl + v;   // global sentinel
}

// fill: scatter edge sources into the shared ss array at global positions
__global__ void fill_k(const int* __restrict__ src, const int* __restrict__ dst,
                       int* __restrict__ fill, int* __restrict__ ssrc, int E)
{
    int e = blockIdx.x * 256 + threadIdx.x;
    if (e < E) {
        int p = atomicAdd(&fill[dst[e]], 1);
        ssrc[p] = src[e];
    }
}

// ---------------- gather-mean: one wave per destination node -----------------
__global__ void gather_mean_k(const ushort* __restrict__ h, const int* __restrict__ rowptr,
                              const int* __restrict__ ssrc, ushort* __restrict__ out, int N)
{
    int i = blockIdx.x * 4 + (threadIdx.x >> 6);
    int lane = threadIdx.x & 63;
    int s0 = rowptr[i], s1 = rowptr[i + 1];
    float a0 = 0.f, a1 = 0.f;
    int e = s0;
    for (; e + 4 <= s1; e += 4) {
        int j0 = ssrc[e], j1 = ssrc[e + 1], j2 = ssrc[e + 2], j3 = ssrc[e + 3];
        uint32_t v0 = *(const uint32_t*)(h + (size_t)j0 * 128 + lane * 2);
        uint32_t v1 = *(const uint32_t*)(h + (size_t)j1 * 128 + lane * 2);
        uint32_t v2 = *(const uint32_t*)(h + (size_t)j2 * 128 + lane * 2);
        uint32_t v3 = *(const uint32_t*)(h + (size_t)j3 * 128 + lane * 2);
        a0 += bflo(v0) + bflo(v1) + bflo(v2) + bflo(v3);
        a1 += bfhi(v0) + bfhi(v1) + bfhi(v2) + bfhi(v3);
    }
    for (; e < s1; ++e) {
        uint32_t v = *(const uint32_t*)(h + (size_t)ssrc[e] * 128 + lane * 2);
        a0 += bflo(v);
        a1 += bfhi(v);
    }
    float inv = 1.0f / fmaxf((float)(s1 - s0), 1.0f);
    ushort2 o;
    o.x = f2bf(a0 * inv);
    o.y = f2bf(a1 * inv);
    *(ushort2*)(out + (size_t)i * 128 + lane * 2) = o;
}

// ---------------- multi-source GEMM: out = relu(sum_i A_i @ W_i + bias) ------
__launch_bounds__(256, 2)
__global__ void gemm_k(const ushort* __restrict__ A0, const ushort* __restrict__ A1,
                       const ushort* __restrict__ A2, const ushort* __restrict__ A3,
                       const ushort* __restrict__ W0, const ushort* __restrict__ W1,
                       const ushort* __restrict__ W2, const ushort* __restrict__ W3,
                       const float* __restrict__ bias, ushort* __restrict__ out, int nsrc)
{
    __shared__ ushort a_lds[128][72];
    __shared__ ushort w_lds[128][72];
    const int tid = threadIdx.x;
    const int lane = tid & 63, wave = tid >> 6;
    const int wr = wave >> 1, wc = wave & 1;
    const size_t r0 = (size_t)blockIdx.x * 128;

    f32x4 acc[4][4];
    const f32x4 zero = {0.f, 0.f, 0.f, 0.f};
#pragma unroll
    for (int m = 0; m < 4; ++m)
#pragma unroll
        for (int n = 0; n < 4; ++n) acc[m][n] = zero;

    const ushort* As[4] = {A0, A1, A2, A3};
    const ushort* Ws[4] = {W0, W1, W2, W3};

    for (int s = 0; s < nsrc; ++s) {
        const ushort* Ap = As[s] + r0 * 128;
        const ushort* Wp = Ws[s];
        for (int k0 = 0; k0 < 128; k0 += 64) {
            __syncthreads();
#pragma unroll
            for (int j = 0; j < 4; ++j) {
                int idx = (j * 256 + tid) * 8;
                int r = idx >> 6, c = idx & 63;
                *(uint4*)&a_lds[r][c] = *(const uint4*)(Ap + r * 128 + k0 + c);
                *(uint4*)&w_lds[r][c] = *(const uint4*)(Wp + r * 128 + k0 + c);
            }
            __syncthreads();
#pragma unroll
            for (int ks = 0; ks < 64; ks += 32) {
                short8 af[4], bfr[4];
                int col = ks + ((lane >> 4) << 3);
                int ra = (wr << 6) + (lane & 15);
                int rb = (wc << 6) + (lane & 15);
#pragma unroll
                for (int m = 0; m < 4; ++m) af[m] = *(const short8*)&a_lds[ra + m * 16][col];
#pragma unroll
                for (int n = 0; n < 4; ++n) bfr[n] = *(const short8*)&w_lds[rb + n * 16][col];
#pragma unroll
                for (int m = 0; m < 4; ++m)
#pragma unroll
                    for (int n = 0; n < 4; ++n)
                        acc[m][n] = __builtin_amdgcn_mfma_f32_16x16x32_bf16(
                            af[m], bfr[n], acc[m][n], 0, 0, 0);
            }
        }
    }

    const int rbase = (wr << 6) + ((lane >> 4) << 2);
    const int cbase = (wc << 6) + (lane & 15);
#pragma unroll
    for (int m = 0; m < 4; ++m)
#pragma unroll
        for (int n = 0; n < 4; ++n) {
            int coln = cbase + n * 16;
            float bcol = bias[coln];
#pragma unroll
            for (int rg = 0; rg < 4; ++rg) {
                int row = rbase + m * 16 + rg;
                float v = acc[m][n][rg] + bcol;
                v = fmaxf(v, 0.f);
                out[(r0 + row) * 128 + coln] = f2bf(v);
            }
        }
}

// ---------------- pooling gate: gate[i] = h_p[i]·Wg + bg ---------------------
__global__ void gate_k(const ushort* __restrict__ hp, const float* __restrict__ Wg,
                       const float* __restrict__ bg, float* __restrict__ gate)
{
    int lane = threadIdx.x & 63;
    int wave = threadIdx.x >> 6;
    int i = blockIdx.x * 4 + wave;
    ushort2 h2 = *(const ushort2*)(hp + (size_t)i * 128 + lane * 2);
    float2 w2 = *(const float2*)(Wg + lane * 2);
    float g = bf2f(h2.x) * w2.x + bf2f(h2.y) * w2.y;
    for (int off = 32; off; off >>= 1) g += __shfl_down(g, off);
    if (lane == 0) gate[i] = g + bg[0];
}

// ---------------- segment softmax + weighted sum -> emb[B,128] ---------------
__global__ void pool_k(const float* __restrict__ gate, const ushort* __restrict__ hp,
                       const int* __restrict__ batch,
                       float* __restrict__ ew, float* __restrict__ emb)
{
    __shared__ float red[256];
    __shared__ int sb[2];
    __shared__ float sm, sden;
    int b = blockIdx.x, t = threadIdx.x;
    if (t < 2) {
        int target = b + t;
        int lo = 0, hi = NP;
        while (lo < hi) { int mid = (lo + hi) >> 1; if (batch[mid] < target) lo = mid + 1; else hi = mid; }
        sb[t] = lo;
    }
    __syncthreads();
    int s = sb[0], e = sb[1];

    // segment max
    float lm = -3.4e38f;
    for (int i = s + t; i < e; i += 256) lm = fmaxf(lm, gate[i]);
    red[t] = lm; __syncthreads();
    for (int o = 128; o; o >>= 1) { if (t < o) red[t] = fmaxf(red[t], red[t + o]); __syncthreads(); }
    if (t == 0) sm = red[0];
    __syncthreads();
    float m = sm;

    // exp + denom
    float loc = 0.f;
    for (int i = s + t; i < e; i += 256) {
        float w = expf(gate[i] - m);
        ew[i] = w;
        loc += w;
    }
    red[t] = loc; __syncthreads();
    for (int o = 128; o; o >>= 1) { if (t < o) red[t] += red[t + o]; __syncthreads(); }
    if (t == 0) sden = red[0];
    __syncthreads();
    float inv = (e > s) ? 1.0f / sden : 0.f;

    // weighted sum
    int c = t & 127, half = t >> 7;
    float acc = 0.f;
    for (int i = s + half; i < e; i += 2) acc += ew[i] * bf2f(hp[(size_t)i * 128 + c]);
    __syncthreads();
    red[t] = acc; __syncthreads();
    if (t < 128) emb[b * 128 + c] = (red[c] + red[c + 128]) * inv;
}

// ---------------- actor/critic heads ----------------------------------------
__global__ void heads_k(const float* __restrict__ emb,
                        const float* __restrict__ Wa1, const float* __restrict__ ba1,
                        const float* __restrict__ Wa2, const float* __restrict__ ba2,
                        const float* __restrict__ Wc1, const float* __restrict__ bc1,
                        const float* __restrict__ Wc2, const float* __restrict__ bc2,
                        float* __restrict__ outL, float* __restrict__ outV)
{
    __shared__ float er[128], ha[128], hc[128], red[128];
    int b = blockIdx.x, t = threadIdx.x;
    if (t < 128) er[t] = emb[b * 128 + t];
    __syncthreads();
    if (t < 128) {
        float a = ba1[t];
        for (int k = 0; k < 128; ++k) a += er[k] * Wa1[k * 128 + t];
        ha[t] = fmaxf(a, 0.f);
    } else {
        int c = t - 128;
        float a = bc1[c];
        for (int k = 0; k < 128; ++k) a += er[k] * Wc1[k * 128 + c];
        hc[c] = fmaxf(a, 0.f);
    }
    __syncthreads();
    {
        float a = ba2[t];
        for (int k = 0; k < 128; ++k) a += ha[k] * Wa2[k * 256 + t];
        outL[b * 256 + t] = a;
    }
    if (t < 128) red[t] = hc[t] * Wc2[t];
    __syncthreads();
    for (int o = 64; o; o >>= 1) { if (t < o) red[t] += red[t + o]; __syncthreads(); }
    if (t == 0) outV[b] = red[0] + bc2[0];
}

// ============================================================================
extern "C" void kernel_launch(void* const* d_in, const int* in_sizes, int n_in,
                              void* d_out, int out_size, void* d_ws, size_t ws_size,
                              hipStream_t stream)
{
    const float* x_phys = (const float*)d_in[0];
    const float* x_log  = (const float*)d_in[1];
    const float* x_gate = (const float*)d_in[2];
    const int*   batch  = (const int*)d_in[3];
    const int* intra_s = (const int*)d_in[4];  const int* intra_d = (const int*)d_in[5];
    const int* inter_s = (const int*)d_in[6];  const int* inter_d = (const int*)d_in[7];
    const int* map_s   = (const int*)d_in[8];  const int* map_d   = (const int*)d_in[9];
    const int* part_s  = (const int*)d_in[10]; const int* part_d  = (const int*)d_in[11];
    const int* dep_s   = (const int*)d_in[12]; const int* dep_d   = (const int*)d_in[13];
    const int E_INTRA = in_sizes[4], E_INTER = in_sizes[6], E_MAP = in_sizes[8],
              E_PART = in_sizes[10], E_DEP = in_sizes[12];
    const int E_TOT = E_INTRA + E_INTER + E_MAP + E_PART + E_DEP;

    const float* W_phys = (const float*)d_in[14]; const float* b_phys = (const float*)d_in[15];
    const float* W_log  = (const float*)d_in[16]; const float* b_log  = (const float*)d_in[17];
    const float* W_gate = (const float*)d_in[18]; const float* b_gate = (const float*)d_in[19];
    const float* Wl1 = (const float*)d_in[20]; const float* bl1 = (const float*)d_in[21];
    const float* Wr1 = (const float*)d_in[22];
    const float* Wl2 = (const float*)d_in[23]; const float* bl2 = (const float*)d_in[24];
    const float* Wr2 = (const float*)d_in[25];
    const float* Wg  = (const float*)d_in[26]; const float* bg  = (const float*)d_in[27];
    const float* Wa1 = (const float*)d_in[28]; const float* ba1 = (const float*)d_in[29];
    const float* Wa2 = (const float*)d_in[30]; const float* ba2 = (const float*)d_in[31];
    const float* Wc1 = (const float*)d_in[32]; const float* bc1 = (const float*)d_in[33];
    const float* Wc2 = (const float*)d_in[34]; const float* bc2 = (const float*)d_in[35];

    float* outL = (float*)d_out;
    float* outV = outL + NBAT * AD;

    // ---- carve workspace ----
    char* wsp = (char*)d_ws;
    size_t off = 0;
    auto alloc = [&](size_t sz) -> void* {
        void* p = wsp + off;
        off = (off + sz + 255) & ~(size_t)255;
        return p;
    };
    ushort* hp    = (ushort*)alloc((size_t)NP * 128 * 2);
    ushort* hl    = (ushort*)alloc((size_t)NL * 128 * 2);
    ushort* hg    = (ushort*)alloc((size_t)NG * 128 * 2);
    ushort* aggbA = (ushort*)alloc((size_t)NP * 128 * 2);  // intra mean
    ushort* aggbB = (ushort*)alloc((size_t)NP * 128 * 2);  // inter mean
    ushort* Mmap  = (ushort*)alloc((size_t)NP * 128 * 2);  // mean(h_l) over map
    ushort* aggbD = (ushort*)alloc((size_t)NG * 128 * 2);  // dep mean
    ushort* Mpart = (ushort*)alloc((size_t)NG * 128 * 2);  // mean(h_l) over part

    // Concatenated CSR: type order intra | inter | map | part | dep.
    // rowptr holds GLOBAL offsets into the single ss array.
    int* hist     = (int*)alloc((size_t)NTOT * 4);
    int* rowptr   = (int*)alloc((size_t)(NTOT + 1) * 4);
    int* fill     = (int*)alloc((size_t)NTOT * 4);
    int* partials = (int*)alloc((size_t)SCAN_B * 4);
    int* ss       = (int*)alloc((size_t)E_TOT * 4);
    const int off_intra = 0, off_inter = NP, off_map = 2 * NP,
              off_part = 3 * NP, off_dep = 3 * NP + NG;

    float*  gate = (float*)alloc((size_t)NP * 4);
    float*  ew   = (float*)alloc((size_t)NP * 4);
    float*  emb  = (float*)alloc(NBAT * 128 * 4);
    ushort* wlt  = (ushort*)alloc((size_t)2 * 7 * 16384 * 2);
    float*  bsum = (float*)alloc(2 * 256 * 4);
    (void)ws_size; (void)out_size; (void)n_in;

    // ---- weight prep + encoders ----
    prep_w<<<15, 256, 0, stream>>>(Wl1, Wr1, bl1, Wl2, Wr2, bl2, wlt, bsum);
    encode_k<<<NP / 2, 256, 0, stream>>>(x_phys, W_phys, b_phys, hp, 5);
    encode_k<<<NL / 2, 256, 0, stream>>>(x_log, W_log, b_log, hl, 1);
    encode_k<<<NG / 2, 256, 0, stream>>>(x_gate, W_gate, b_gate, hg, 2);

    // ---- CSR build (once; reused across both layers) ----
    hipMemsetAsync(hist, 0, (size_t)NTOT * 4, stream);
    hist_k<<<(E_INTRA + 255) / 256, 256, 0, stream>>>(intra_d, hist + off_intra, E_INTRA);
    hist_k<<<(E_INTER + 255) / 256, 256, 0, stream>>>(inter_d, hist + off_inter, E_INTER);
    hist_k<<<(E_MAP + 255) / 256, 256, 0, stream>>>(map_d, hist + off_map, E_MAP);
    hist_k<<<(E_PART + 255) / 256, 256, 0, stream>>>(part_d, hist + off_part, E_PART);
    hist_k<<<(E_DEP + 255) / 256, 256, 0, stream>>>(dep_d, hist + off_dep, E_DEP);
    scanA_k<<<SCAN_B, 256, 0, stream>>>(hist, partials);
    scanB_k<<<1, 1024, 0, stream>>>(partials);
    scanC_k<<<SCAN_B, 256, 0, stream>>>(hist, partials, rowptr, fill);
    fill_k<<<(E_INTRA + 255) / 256, 256, 0, stream>>>(intra_s, intra_d, fill + off_intra, ss, E_INTRA);
    fill_k<<<(E_INTER + 255) / 256, 256, 0, stream>>>(inter_s, inter_d, fill + off_inter, ss, E_INTER);
    fill_k<<<(E_MAP + 255) / 256, 256, 0, stream>>>(map_s, map_d, fill + off_map, ss, E_MAP);
    fill_k<<<(E_PART + 255) / 256, 256, 0, stream>>>(part_s, part_d, fill + off_part, ss, E_PART);
    fill_k<<<(E_DEP + 255) / 256, 256, 0, stream>>>(dep_s, dep_d, fill + off_dep, ss, E_DEP);

    // ---- static aggregations from h_l (reused by both layers) ----
    gather_mean_k<<<NP / 4, 256, 0, stream>>>(hl, rowptr + off_map, ss, Mmap, NP);
    gather_mean_k<<<NG / 4, 256, 0, stream>>>(hl, rowptr + off_part, ss, Mpart, NG);

    // ---- two hetero layers ----
    for (int l = 0; l < 2; ++l) {
        const ushort* wl = wlt + (size_t)l * 7 * 16384;
        const float* blp = bsum + l * 256;
        const float* blg = blp + 128;

        gather_mean_k<<<NP / 4, 256, 0, stream>>>(hp, rowptr + off_intra, ss, aggbA, NP);
        gather_mean_k<<<NP / 4, 256, 0, stream>>>(hp, rowptr + off_inter, ss, aggbB, NP);
        gather_mean_k<<<NG / 4, 256, 0, stream>>>(hg, rowptr + off_dep, ss, aggbD, NG);

        // out_p = relu(meanI@Wl0 + meanT@Wl1 + Mmap@Wl2 + hp@(Wr0+Wr1+Wr2) + blp)
        gemm_k<<<NP / 128, 256, 0, stream>>>(aggbA, aggbB, Mmap, hp,
                                             wl + 0 * 16384, wl + 1 * 16384,
                                             wl + 2 * 16384, wl + 5 * 16384,
                                             blp, hp, 4);
        // out_g = relu(Mpart@Wl3 + meanD@Wl4 + hg@(Wr3+Wr4) + blg)
        gemm_k<<<NG / 128, 256, 0, stream>>>(Mpart, aggbD, hg, nullptr,
                                             wl + 3 * 16384, wl + 4 * 16384,
                                             wl + 6 * 16384, nullptr,
                                             blg, hg, 3);
    }

    // ---- attentional pooling + heads ----
    gate_k<<<NP / 4, 256, 0, stream>>>(hp, Wg, bg, gate);
    pool_k<<<NBAT, 256, 0, stream>>>(gate, hp, batch, ew, emb);
    heads_k<<<NBAT, 256, 0, stream>>>(emb, Wa1, ba1, Wa2, ba2, Wc1, bc1, Wc2, bc2, outL, outV);
}

// Round 8
// 517.838 us; speedup vs baseline: 14.6071x; 1.5177x over previous
//
#include <hip/hip_runtime.h>
#include <stdint.h>

#define H    128
#define NBAT 128
#define AD   256
#define NP   65536
#define NL   32768
#define NTOT2 (3 * NP)              // intra | inter | map concatenated CSR nodes
#define SCAN_B (NTOT2 / 256)        // 768 scan blocks

typedef __attribute__((ext_vector_type(8))) short short8;
typedef __attribute__((ext_vector_type(4))) float f32x4;

__device__ __forceinline__ ushort f2bf(float f) {
    uint32_t u = __float_as_uint(f);
    u += 0x7FFFu + ((u >> 16) & 1u);
    return (ushort)(u >> 16);
}
__device__ __forceinline__ float bf2f(ushort h) {
    return __uint_as_float(((uint32_t)h) << 16);
}
__device__ __forceinline__ float bflo(uint32_t v) { return __uint_as_float(v << 16); }
__device__ __forceinline__ float bfhi(uint32_t v) { return __uint_as_float(v & 0xFFFF0000u); }

// ---------------- weight prep ------------------------------------------------
// Gate-node branch is DEAD CODE (h_g never feeds the pooled h_p outputs), so
// only the physical-node update weights survive: per layer
//   r=0..2 : Wl[0..2] transposed;  r=3 : (Wr0+Wr1+Wr2) transposed
// bsum[l][0:128] = bl0+bl1+bl2.
__global__ void prep_w(const float* __restrict__ Wl1, const float* __restrict__ Wr1,
                       const float* __restrict__ bl1,
                       const float* __restrict__ Wl2, const float* __restrict__ Wr2,
                       const float* __restrict__ bl2,
                       ushort* __restrict__ wlt,  // [2][4][128*128] (n-major)
                       float* __restrict__ bsum)  // [2][128]
{
    int m = blockIdx.x;
    if (m < 8) {
        int l = m >> 2, r = m & 3;
        const float* Wl = l ? Wl2 : Wl1;
        const float* Wr = l ? Wr2 : Wr1;
        ushort* dst = wlt + (size_t)m * 16384;
        for (int it = 0; it < 64; ++it) {
            int idx = it * 256 + threadIdx.x;
            int k = idx >> 7, n = idx & 127;
            float v;
            if (r < 3) v = Wl[r * 16384 + k * 128 + n];
            else       v = Wr[0 * 16384 + k * 128 + n] + Wr[1 * 16384 + k * 128 + n]
                         + Wr[2 * 16384 + k * 128 + n];
            dst[n * 128 + k] = f2bf(v);
        }
    } else {
        int t = threadIdx.x;
        if (t < 128) {
            bsum[t]       = bl1[t] + bl1[128 + t] + bl1[256 + t];
            bsum[128 + t] = bl2[t] + bl2[128 + t] + bl2[256 + t];
        }
    }
}

// ---------------- encoders: h = relu(x @ W + b) -> bf16 ----------------------
__global__ void encode_k(const float* __restrict__ x, const float* __restrict__ W,
                         const float* __restrict__ b, ushort* __restrict__ out, int K)
{
    int t = threadIdx.x;
    int i = blockIdx.x * 2 + (t >> 7);
    int c = t & 127;
    float acc = b[c];
    for (int k = 0; k < K; ++k) acc += x[(size_t)i * K + k] * W[k * 128 + c];
    out[(size_t)i * 128 + c] = f2bf(fmaxf(acc, 0.f));
}

// ---------------- CSR build over concatenated intra|inter|map ---------------
__global__ void hist3_k(const int* __restrict__ intra_d, const int* __restrict__ inter_d,
                        const int* __restrict__ map_d, int Ei, int Et, int Em,
                        int* __restrict__ hist)
{
    int e = blockIdx.x * 256 + threadIdx.x;
    int d;
    if (e < Ei)                 d = intra_d[e];
    else if (e < Ei + Et)       d = NP + inter_d[e - Ei];
    else if (e < Ei + Et + Em)  d = 2 * NP + map_d[e - Ei - Et];
    else return;
    atomicAdd(&hist[d], 1);
}

// A: per-block (256-elem) sums
__global__ void scanA_k(const int* __restrict__ hist, int* __restrict__ partials)
{
    __shared__ int red[256];
    int t = threadIdx.x;
    red[t] = hist[blockIdx.x * 256 + t];
    __syncthreads();
    for (int o = 128; o; o >>= 1) { if (t < o) red[t] += red[t + o]; __syncthreads(); }
    if (t == 0) partials[blockIdx.x] = red[0];
}

// B: one block exclusive-scans the partials in place
__global__ void scanB_k(int* __restrict__ partials)
{
    __shared__ int lds[1024];
    int t = threadIdx.x;
    int v0 = (2 * t     < SCAN_B) ? partials[2 * t]     : 0;
    int v1 = (2 * t + 1 < SCAN_B) ? partials[2 * t + 1] : 0;
    lds[t] = v0 + v1;
    __syncthreads();
    for (int d = 1; d < 1024; d <<= 1) {
        int v = (t >= d) ? lds[t - d] : 0;
        __syncthreads();
        lds[t] += v;
        __syncthreads();
    }
    int base = (t == 0) ? 0 : lds[t - 1];
    if (2 * t     < SCAN_B) partials[2 * t]     = base;
    if (2 * t + 1 < SCAN_B) partials[2 * t + 1] = base + v0;
}

// C: local scan + base -> rowptr (global offsets) + fill copy
__global__ void scanC_k(const int* __restrict__ hist, const int* __restrict__ partials,
                        int* __restrict__ rowptr, int* __restrict__ fill)
{
    __shared__ int lds[256];
    int t = threadIdx.x;
    int idx = blockIdx.x * 256 + t;
    int v = hist[idx];
    lds[t] = v;
    __syncthreads();
    for (int d = 1; d < 256; d <<= 1) {
        int x = (t >= d) ? lds[t - d] : 0;
        __syncthreads();
        lds[t] += x;
        __syncthreads();
    }
    int excl = lds[t] - v + partials[blockIdx.x];
    rowptr[idx] = excl;
    fill[idx] = excl;
    if (idx == NTOT2 - 1) rowptr[NTOT2] = excl + v;   // global sentinel
}

__global__ void fill3_k(const int* __restrict__ intra_s, const int* __restrict__ intra_d,
                        const int* __restrict__ inter_s, const int* __restrict__ inter_d,
                        const int* __restrict__ map_s, const int* __restrict__ map_d,
                        int Ei, int Et, int Em,
                        int* __restrict__ fill, int* __restrict__ ssrc)
{
    int e = blockIdx.x * 256 + threadIdx.x;
    int s, d;
    if (e < Ei)                { s = intra_s[e];          d = intra_d[e]; }
    else if (e < Ei + Et)      { int k = e - Ei;      s = inter_s[k]; d = NP + inter_d[k]; }
    else if (e < Ei + Et + Em) { int k = e - Ei - Et; s = map_s[k];   d = 2 * NP + map_d[k]; }
    else return;
    int p = atomicAdd(&fill[d], 1);
    ssrc[p] = s;
}

// ---------------- gather-mean: one wave per destination node -----------------
__global__ void gather_mean_k(const ushort* __restrict__ h, const int* __restrict__ rowptr,
                              const int* __restrict__ ssrc, ushort* __restrict__ out, int N)
{
    int i = blockIdx.x * 4 + (threadIdx.x >> 6);
    int lane = threadIdx.x & 63;
    int s0 = rowptr[i], s1 = rowptr[i + 1];
    float a0 = 0.f, a1 = 0.f;
    int e = s0;
    for (; e + 4 <= s1; e += 4) {
        int j0 = ssrc[e], j1 = ssrc[e + 1], j2 = ssrc[e + 2], j3 = ssrc[e + 3];
        uint32_t v0 = *(const uint32_t*)(h + (size_t)j0 * 128 + lane * 2);
        uint32_t v1 = *(const uint32_t*)(h + (size_t)j1 * 128 + lane * 2);
        uint32_t v2 = *(const uint32_t*)(h + (size_t)j2 * 128 + lane * 2);
        uint32_t v3 = *(const uint32_t*)(h + (size_t)j3 * 128 + lane * 2);
        a0 += bflo(v0) + bflo(v1) + bflo(v2) + bflo(v3);
        a1 += bfhi(v0) + bfhi(v1) + bfhi(v2) + bfhi(v3);
    }
    for (; e < s1; ++e) {
        uint32_t v = *(const uint32_t*)(h + (size_t)ssrc[e] * 128 + lane * 2);
        a0 += bflo(v);
        a1 += bfhi(v);
    }
    float inv = 1.0f / fmaxf((float)(s1 - s0), 1.0f);
    ushort2 o;
    o.x = f2bf(a0 * inv);
    o.y = f2bf(a1 * inv);
    *(ushort2*)(out + (size_t)i * 128 + lane * 2) = o;
}

// intra + inter means in one launch: waves [0,NP) -> aggbA, [NP,2NP) -> aggbB
__global__ void gather2_k(const ushort* __restrict__ hp, const int* __restrict__ rowptr,
                          const int* __restrict__ ssrc,
                          ushort* __restrict__ outA, ushort* __restrict__ outB)
{
    int g = blockIdx.x * 4 + (threadIdx.x >> 6);     // 0 .. 2*NP-1
    int lane = threadIdx.x & 63;
    ushort* out = (g < NP) ? outA : outB;
    int i = (g < NP) ? g : (g - NP);
    int s0 = rowptr[g], s1 = rowptr[g + 1];          // rowptr is concatenated: works directly
    float a0 = 0.f, a1 = 0.f;
    int e = s0;
    for (; e + 4 <= s1; e += 4) {
        int j0 = ssrc[e], j1 = ssrc[e + 1], j2 = ssrc[e + 2], j3 = ssrc[e + 3];
        uint32_t v0 = *(const uint32_t*)(hp + (size_t)j0 * 128 + lane * 2);
        uint32_t v1 = *(const uint32_t*)(hp + (size_t)j1 * 128 + lane * 2);
        uint32_t v2 = *(const uint32_t*)(hp + (size_t)j2 * 128 + lane * 2);
        uint32_t v3 = *(const uint32_t*)(hp + (size_t)j3 * 128 + lane * 2);
        a0 += bflo(v0) + bflo(v1) + bflo(v2) + bflo(v3);
        a1 += bfhi(v0) + bfhi(v1) + bfhi(v2) + bfhi(v3);
    }
    for (; e < s1; ++e) {
        uint32_t v = *(const uint32_t*)(hp + (size_t)ssrc[e] * 128 + lane * 2);
        a0 += bflo(v);
        a1 += bfhi(v);
    }
    float inv = 1.0f / fmaxf((float)(s1 - s0), 1.0f);
    ushort2 o;
    o.x = f2bf(a0 * inv);
    o.y = f2bf(a1 * inv);
    *(ushort2*)(out + (size_t)i * 128 + lane * 2) = o;
}

// ---------------- multi-source GEMM: out = relu(sum_i A_i @ W_i + bias) ------
__launch_bounds__(256, 2)
__global__ void gemm_k(const ushort* __restrict__ A0, const ushort* __restrict__ A1,
                       const ushort* __restrict__ A2, const ushort* __restrict__ A3,
                       const ushort* __restrict__ W0, const ushort* __restrict__ W1,
                       const ushort* __restrict__ W2, const ushort* __restrict__ W3,
                       const float* __restrict__ bias, ushort* __restrict__ out, int nsrc)
{
    __shared__ ushort a_lds[128][72];
    __shared__ ushort w_lds[128][72];
    const int tid = threadIdx.x;
    const int lane = tid & 63, wave = tid >> 6;
    const int wr = wave >> 1, wc = wave & 1;
    const size_t r0 = (size_t)blockIdx.x * 128;

    f32x4 acc[4][4];
    const f32x4 zero = {0.f, 0.f, 0.f, 0.f};
#pragma unroll
    for (int m = 0; m < 4; ++m)
#pragma unroll
        for (int n = 0; n < 4; ++n) acc[m][n] = zero;

    const ushort* As[4] = {A0, A1, A2, A3};
    const ushort* Ws[4] = {W0, W1, W2, W3};

    for (int s = 0; s < nsrc; ++s) {
        const ushort* Ap = As[s] + r0 * 128;
        const ushort* Wp = Ws[s];
        for (int k0 = 0; k0 < 128; k0 += 64) {
            __syncthreads();
#pragma unroll
            for (int j = 0; j < 4; ++j) {
                int idx = (j * 256 + tid) * 8;
                int r = idx >> 6, c = idx & 63;
                *(uint4*)&a_lds[r][c] = *(const uint4*)(Ap + r * 128 + k0 + c);
                *(uint4*)&w_lds[r][c] = *(const uint4*)(Wp + r * 128 + k0 + c);
            }
            __syncthreads();
#pragma unroll
            for (int ks = 0; ks < 64; ks += 32) {
                short8 af[4], bfr[4];
                int col = ks + ((lane >> 4) << 3);
                int ra = (wr << 6) + (lane & 15);
                int rb = (wc << 6) + (lane & 15);
#pragma unroll
                for (int m = 0; m < 4; ++m) af[m] = *(const short8*)&a_lds[ra + m * 16][col];
#pragma unroll
                for (int n = 0; n < 4; ++n) bfr[n] = *(const short8*)&w_lds[rb + n * 16][col];
#pragma unroll
                for (int m = 0; m < 4; ++m)
#pragma unroll
                    for (int n = 0; n < 4; ++n)
                        acc[m][n] = __builtin_amdgcn_mfma_f32_16x16x32_bf16(
                            af[m], bfr[n], acc[m][n], 0, 0, 0);
            }
        }
    }

    const int rbase = (wr << 6) + ((lane >> 4) << 2);
    const int cbase = (wc << 6) + (lane & 15);
#pragma unroll
    for (int m = 0; m < 4; ++m)
#pragma unroll
        for (int n = 0; n < 4; ++n) {
            int coln = cbase + n * 16;
            float bcol = bias[coln];
#pragma unroll
            for (int rg = 0; rg < 4; ++rg) {
                int row = rbase + m * 16 + rg;
                float v = acc[m][n][rg] + bcol;
                v = fmaxf(v, 0.f);
                out[(r0 + row) * 128 + coln] = f2bf(v);
            }
        }
}

// ---------------- pooling gate: gate[i] = h_p[i]·Wg + bg ---------------------
__global__ void gate_k(const ushort* __restrict__ hp, const float* __restrict__ Wg,
                       const float* __restrict__ bg, float* __restrict__ gate)
{
    int lane = threadIdx.x & 63;
    int wave = threadIdx.x >> 6;
    int i = blockIdx.x * 4 + wave;
    ushort2 h2 = *(const ushort2*)(hp + (size_t)i * 128 + lane * 2);
    float2 w2 = *(const float2*)(Wg + lane * 2);
    float g = bf2f(h2.x) * w2.x + bf2f(h2.y) * w2.y;
    for (int off = 32; off; off >>= 1) g += __shfl_down(g, off);
    if (lane == 0) gate[i] = g + bg[0];
}

// ---------------- segment softmax + weighted sum -> emb[B,128] ---------------
__global__ void pool_k(const float* __restrict__ gate, const ushort* __restrict__ hp,
                       const int* __restrict__ batch,
                       float* __restrict__ ew, float* __restrict__ emb)
{
    __shared__ float red[256];
    __shared__ int sb[2];
    __shared__ float sm, sden;
    int b = blockIdx.x, t = threadIdx.x;
    if (t < 2) {
        int target = b + t;
        int lo = 0, hi = NP;
        while (lo < hi) { int mid = (lo + hi) >> 1; if (batch[mid] < target) lo = mid + 1; else hi = mid; }
        sb[t] = lo;
    }
    __syncthreads();
    int s = sb[0], e = sb[1];

    float lm = -3.4e38f;
    for (int i = s + t; i < e; i += 256) lm = fmaxf(lm, gate[i]);
    red[t] = lm; __syncthreads();
    for (int o = 128; o; o >>= 1) { if (t < o) red[t] = fmaxf(red[t], red[t + o]); __syncthreads(); }
    if (t == 0) sm = red[0];
    __syncthreads();
    float m = sm;

    float loc = 0.f;
    for (int i = s + t; i < e; i += 256) {
        float w = expf(gate[i] - m);
        ew[i] = w;
        loc += w;
    }
    red[t] = loc; __syncthreads();
    for (int o = 128; o; o >>= 1) { if (t < o) red[t] += red[t + o]; __syncthreads(); }
    if (t == 0) sden = red[0];
    __syncthreads();
    float inv = (e > s) ? 1.0f / sden : 0.f;

    int c = t & 127, half = t >> 7;
    float acc = 0.f;
    for (int i = s + half; i < e; i += 2) acc += ew[i] * bf2f(hp[(size_t)i * 128 + c]);
    __syncthreads();
    red[t] = acc; __syncthreads();
    if (t < 128) emb[b * 128 + c] = (red[c] + red[c + 128]) * inv;
}

// ---------------- actor/critic heads ----------------------------------------
__global__ void heads_k(const float* __restrict__ emb,
                        const float* __restrict__ Wa1, const float* __restrict__ ba1,
                        const float* __restrict__ Wa2, const float* __restrict__ ba2,
                        const float* __restrict__ Wc1, const float* __restrict__ bc1,
                        const float* __restrict__ Wc2, const float* __restrict__ bc2,
                        float* __restrict__ outL, float* __restrict__ outV)
{
    __shared__ float er[128], ha[128], hc[128], red[128];
    int b = blockIdx.x, t = threadIdx.x;
    if (t < 128) er[t] = emb[b * 128 + t];
    __syncthreads();
    if (t < 128) {
        float a = ba1[t];
        for (int k = 0; k < 128; ++k) a += er[k] * Wa1[k * 128 + t];
        ha[t] = fmaxf(a, 0.f);
    } else {
        int c = t - 128;
        float a = bc1[c];
        for (int k = 0; k < 128; ++k) a += er[k] * Wc1[k * 128 + c];
        hc[c] = fmaxf(a, 0.f);
    }
    __syncthreads();
    {
        float a = ba2[t];
        for (int k = 0; k < 128; ++k) a += ha[k] * Wa2[k * 256 + t];
        outL[b * 256 + t] = a;
    }
    if (t < 128) red[t] = hc[t] * Wc2[t];
    __syncthreads();
    for (int o = 64; o; o >>= 1) { if (t < o) red[t] += red[t + o]; __syncthreads(); }
    if (t == 0) outV[b] = red[0] + bc2[0];
}

// ============================================================================
extern "C" void kernel_launch(void* const* d_in, const int* in_sizes, int n_in,
                              void* d_out, int out_size, void* d_ws, size_t ws_size,
                              hipStream_t stream)
{
    const float* x_phys = (const float*)d_in[0];
    const float* x_log  = (const float*)d_in[1];
    const int*   batch  = (const int*)d_in[3];
    const int* intra_s = (const int*)d_in[4];  const int* intra_d = (const int*)d_in[5];
    const int* inter_s = (const int*)d_in[6];  const int* inter_d = (const int*)d_in[7];
    const int* map_s   = (const int*)d_in[8];  const int* map_d   = (const int*)d_in[9];
    const int E_INTRA = in_sizes[4], E_INTER = in_sizes[6], E_MAP = in_sizes[8];
    const int E_ALL = E_INTRA + E_INTER + E_MAP;

    const float* W_phys = (const float*)d_in[14]; const float* b_phys = (const float*)d_in[15];
    const float* W_log  = (const float*)d_in[16]; const float* b_log  = (const float*)d_in[17];
    const float* Wl1 = (const float*)d_in[20]; const float* bl1 = (const float*)d_in[21];
    const float* Wr1 = (const float*)d_in[22];
    const float* Wl2 = (const float*)d_in[23]; const float* bl2 = (const float*)d_in[24];
    const float* Wr2 = (const float*)d_in[25];
    const float* Wg  = (const float*)d_in[26]; const float* bg  = (const float*)d_in[27];
    const float* Wa1 = (const float*)d_in[28]; const float* ba1 = (const float*)d_in[29];
    const float* Wa2 = (const float*)d_in[30]; const float* ba2 = (const float*)d_in[31];
    const float* Wc1 = (const float*)d_in[32]; const float* bc1 = (const float*)d_in[33];
    const float* Wc2 = (const float*)d_in[34]; const float* bc2 = (const float*)d_in[35];

    float* outL = (float*)d_out;
    float* outV = outL + NBAT * AD;

    // ---- carve workspace ----
    char* wsp = (char*)d_ws;
    size_t off = 0;
    auto alloc = [&](size_t sz) -> void* {
        void* p = wsp + off;
        off = (off + sz + 255) & ~(size_t)255;
        return p;
    };
    ushort* hp    = (ushort*)alloc((size_t)NP * 128 * 2);
    ushort* hl    = (ushort*)alloc((size_t)NL * 128 * 2);
    ushort* aggbA = (ushort*)alloc((size_t)NP * 128 * 2);  // intra mean
    ushort* aggbB = (ushort*)alloc((size_t)NP * 128 * 2);  // inter mean
    ushort* Mmap  = (ushort*)alloc((size_t)NP * 128 * 2);  // mean(h_l) over map (static)

    // Concatenated CSR: intra | inter | map (global offsets into one ss array)
    int* hist     = (int*)alloc((size_t)NTOT2 * 4);
    int* rowptr   = (int*)alloc((size_t)(NTOT2 + 1) * 4);
    int* fill     = (int*)alloc((size_t)NTOT2 * 4);
    int* partials = (int*)alloc((size_t)SCAN_B * 4);
    int* ss       = (int*)alloc((size_t)E_ALL * 4);
    const int off_map = 2 * NP;

    float*  gate = (float*)alloc((size_t)NP * 4);
    float*  ew   = (float*)alloc((size_t)NP * 4);
    float*  emb  = (float*)alloc(NBAT * 128 * 4);
    ushort* wlt  = (ushort*)alloc((size_t)2 * 4 * 16384 * 2);
    float*  bsum = (float*)alloc(2 * 128 * 4);
    (void)ws_size; (void)out_size; (void)n_in;

    // ---- weight prep + encoders (x_gate encoder is dead code: h_g never
    //      reaches the pooled physical-node outputs) ----
    prep_w<<<9, 256, 0, stream>>>(Wl1, Wr1, bl1, Wl2, Wr2, bl2, wlt, bsum);
    encode_k<<<NP / 2, 256, 0, stream>>>(x_phys, W_phys, b_phys, hp, 5);
    encode_k<<<NL / 2, 256, 0, stream>>>(x_log, W_log, b_log, hl, 1);

    // ---- CSR build (intra|inter|map concatenated; once, reused both layers) ----
    hipMemsetAsync(hist, 0, (size_t)NTOT2 * 4, stream);
    hist3_k<<<(E_ALL + 255) / 256, 256, 0, stream>>>(intra_d, inter_d, map_d,
                                                     E_INTRA, E_INTER, E_MAP, hist);
    scanA_k<<<SCAN_B, 256, 0, stream>>>(hist, partials);
    scanB_k<<<1, 1024, 0, stream>>>(partials);
    scanC_k<<<SCAN_B, 256, 0, stream>>>(hist, partials, rowptr, fill);
    fill3_k<<<(E_ALL + 255) / 256, 256, 0, stream>>>(intra_s, intra_d, inter_s, inter_d,
                                                     map_s, map_d,
                                                     E_INTRA, E_INTER, E_MAP, fill, ss);

    // ---- static map aggregation from h_l (reused by both layers) ----
    gather_mean_k<<<NP / 4, 256, 0, stream>>>(hl, rowptr + off_map, ss, Mmap, NP);

    // ---- two physical-node layers ----
    for (int l = 0; l < 2; ++l) {
        const ushort* wl = wlt + (size_t)l * 4 * 16384;
        const float* blp = bsum + l * 128;

        gather2_k<<<2 * NP / 4, 256, 0, stream>>>(hp, rowptr, ss, aggbA, aggbB);

        // out_p = relu(meanI@Wl0 + meanT@Wl1 + Mmap@Wl2 + hp@(Wr0+Wr1+Wr2) + blp)
        gemm_k<<<NP / 128, 256, 0, stream>>>(aggbA, aggbB, Mmap, hp,
                                             wl + 0 * 16384, wl + 1 * 16384,
                                             wl + 2 * 16384, wl + 3 * 16384,
                                             blp, hp, 4);
    }

    // ---- attentional pooling + heads ----
    gate_k<<<NP / 4, 256, 0, stream>>>(hp, Wg, bg, gate);
    pool_k<<<NBAT, 256, 0, stream>>>(gate, hp, batch, ew, emb);
    heads_k<<<NBAT, 256, 0, stream>>>(emb, Wa1, ba1, Wa2, ba2, Wc1, bc1, Wc2, bc2, outL, outV);
}

// Round 9
// 401.437 us; speedup vs baseline: 18.8426x; 1.2900x over previous
//
#include <hip/hip_runtime.h>
#include <stdint.h>

#define H    128
#define NBAT 128
#define AD   256
#define NP   65536
#define NL   32768
#define NTOT2 (3 * NP)              // intra | inter | map concatenated CSR nodes
#define NB   384                    // coarse buckets (dst >> 9)
#define BKT  512                    // nodes per bucket
#define EPB  4096                   // edges per bin-count/bin-place block

typedef __attribute__((ext_vector_type(8))) short short8;
typedef __attribute__((ext_vector_type(4))) float f32x4;

__device__ __forceinline__ ushort f2bf(float f) {
    uint32_t u = __float_as_uint(f);
    u += 0x7FFFu + ((u >> 16) & 1u);
    return (ushort)(u >> 16);
}
__device__ __forceinline__ float bf2f(ushort h) {
    return __uint_as_float(((uint32_t)h) << 16);
}
__device__ __forceinline__ float bflo(uint32_t v) { return __uint_as_float(v << 16); }
__device__ __forceinline__ float bfhi(uint32_t v) { return __uint_as_float(v & 0xFFFF0000u); }

// ---------------- weight prep (gate branch is dead code) ---------------------
__global__ void prep_w(const float* __restrict__ Wl1, const float* __restrict__ Wr1,
                       const float* __restrict__ bl1,
                       const float* __restrict__ Wl2, const float* __restrict__ Wr2,
                       const float* __restrict__ bl2,
                       ushort* __restrict__ wlt,  // [2][4][128*128] (n-major)
                       float* __restrict__ bsum)  // [2][128]
{
    int m = blockIdx.x;
    if (m < 8) {
        int l = m >> 2, r = m & 3;
        const float* Wl = l ? Wl2 : Wl1;
        const float* Wr = l ? Wr2 : Wr1;
        ushort* dst = wlt + (size_t)m * 16384;
        for (int it = 0; it < 64; ++it) {
            int idx = it * 256 + threadIdx.x;
            int k = idx >> 7, n = idx & 127;
            float v;
            if (r < 3) v = Wl[r * 16384 + k * 128 + n];
            else       v = Wr[0 * 16384 + k * 128 + n] + Wr[1 * 16384 + k * 128 + n]
                         + Wr[2 * 16384 + k * 128 + n];
            dst[n * 128 + k] = f2bf(v);
        }
    } else {
        int t = threadIdx.x;
        if (t < 128) {
            bsum[t]       = bl1[t] + bl1[128 + t] + bl1[256 + t];
            bsum[128 + t] = bl2[t] + bl2[128 + t] + bl2[256 + t];
        }
    }
}

// ---------------- encoders: h = relu(x @ W + b) -> bf16 ----------------------
__global__ void encode_k(const float* __restrict__ x, const float* __restrict__ W,
                         const float* __restrict__ b, ushort* __restrict__ out, int K)
{
    int t = threadIdx.x;
    int i = blockIdx.x * 2 + (t >> 7);
    int c = t & 127;
    float acc = b[c];
    for (int k = 0; k < K; ++k) acc += x[(size_t)i * K + k] * W[k * 128 + c];
    out[(size_t)i * 128 + c] = f2bf(fmaxf(acc, 0.f));
}

// ---------------- CSR build via two-level LDS counting sort ------------------
// P1: per-(bucket, block) counts. No global atomics, no memset needed.
__global__ void binCount_k(const int* __restrict__ intra_d, const int* __restrict__ inter_d,
                           const int* __restrict__ map_d, int Ei, int Et, int Em,
                           int G1, int* __restrict__ cntMat /* [NB][G1] */)
{
    __shared__ int cnt[NB];
    int g = blockIdx.x, t = threadIdx.x;
    for (int b = t; b < NB; b += 256) cnt[b] = 0;
    __syncthreads();
    int Eall = Ei + Et + Em;
    int e0 = g * EPB, e1 = min(e0 + EPB, Eall);
    for (int e = e0 + t; e < e1; e += 256) {
        int d;
        if (e < Ei)           d = intra_d[e];
        else if (e < Ei + Et) d = NP + inter_d[e - Ei];
        else                  d = 2 * NP + map_d[e - Ei - Et];
        atomicAdd(&cnt[d >> 9], 1);
    }
    __syncthreads();
    for (int b = t; b < NB; b += 256) cntMat[b * G1 + g] = cnt[b];
}

// generalized hierarchical exclusive scan (A: block sums, B: scan partials, C: apply)
__global__ void scanA_k(const int* __restrict__ data, int* __restrict__ partials, int n)
{
    __shared__ int red[256];
    int t = threadIdx.x;
    int idx = blockIdx.x * 256 + t;
    red[t] = (idx < n) ? data[idx] : 0;
    __syncthreads();
    for (int o = 128; o; o >>= 1) { if (t < o) red[t] += red[t + o]; __syncthreads(); }
    if (t == 0) partials[blockIdx.x] = red[0];
}

__global__ void scanB_k(int* __restrict__ partials, int np)
{
    __shared__ int lds[1024];
    int t = threadIdx.x;
    int v0 = (2 * t     < np) ? partials[2 * t]     : 0;
    int v1 = (2 * t + 1 < np) ? partials[2 * t + 1] : 0;
    lds[t] = v0 + v1;
    __syncthreads();
    for (int d = 1; d < 1024; d <<= 1) {
        int v = (t >= d) ? lds[t - d] : 0;
        __syncthreads();
        lds[t] += v;
        __syncthreads();
    }
    int base = (t == 0) ? 0 : lds[t - 1];
    if (2 * t     < np) partials[2 * t]     = base;
    if (2 * t + 1 < np) partials[2 * t + 1] = base + v0;
}

__global__ void scanC_k(int* __restrict__ data, const int* __restrict__ partials, int n)
{
    __shared__ int lds[256];
    int t = threadIdx.x;
    int idx = blockIdx.x * 256 + t;
    int v = (idx < n) ? data[idx] : 0;
    lds[t] = v;
    __syncthreads();
    for (int d = 1; d < 256; d <<= 1) {
        int x = (t >= d) ? lds[t - d] : 0;
        __syncthreads();
        lds[t] += x;
        __syncthreads();
    }
    if (idx < n) data[idx] = lds[t] - v + partials[blockIdx.x];  // exclusive, in-place
}

// P3: place edges into bucket-grouped array. Each (block,bucket) region is
// contiguous -> writes coalesce in L2.
__global__ void binPlace_k(const int* __restrict__ intra_s, const int* __restrict__ intra_d,
                           const int* __restrict__ inter_s, const int* __restrict__ inter_d,
                           const int* __restrict__ map_s, const int* __restrict__ map_d,
                           int Ei, int Et, int Em, int G1,
                           const int* __restrict__ baseMat, int2* __restrict__ binned)
{
    __shared__ int cur[NB];
    int g = blockIdx.x, t = threadIdx.x;
    for (int b = t; b < NB; b += 256) cur[b] = baseMat[b * G1 + g];
    __syncthreads();
    int Eall = Ei + Et + Em;
    int e0 = g * EPB, e1 = min(e0 + EPB, Eall);
    for (int e = e0 + t; e < e1; e += 256) {
        int s, d;
        if (e < Ei)           { s = intra_s[e];          d = intra_d[e]; }
        else if (e < Ei + Et) { int k = e - Ei;      s = inter_s[k]; d = NP + inter_d[k]; }
        else                  { int k = e - Ei - Et; s = map_s[k];   d = 2 * NP + map_d[k]; }
        int p = atomicAdd(&cur[d >> 9], 1);
        binned[p] = make_int2(s, d);
    }
}

// P4: per-bucket CSR. Bucket = 512 nodes, ~3.6K contiguous edges; per-node
// hist/scan/cursors all in LDS; ss writes stay within the bucket's ~14KB range.
__global__ void csr_k(const int2* __restrict__ binned, const int* __restrict__ baseMat,
                      int G1, int Eall, int* __restrict__ rowptr, int* __restrict__ ss)
{
    __shared__ int hist[BKT], orig[BKT], cur[BKT];
    int b = blockIdx.x, t = threadIdx.x;
    int bs = baseMat[b * G1];
    int be = (b == NB - 1) ? Eall : baseMat[(b + 1) * G1];

    hist[t] = 0; hist[t + 256] = 0;
    __syncthreads();
    for (int e = bs + t; e < be; e += 256) atomicAdd(&hist[binned[e].y & 511], 1);
    __syncthreads();
    orig[t] = hist[t]; orig[t + 256] = hist[t + 256];
    __syncthreads();
    // inclusive Hillis-Steele over 512 entries, 2 per thread
    for (int d = 1; d < 512; d <<= 1) {
        int v0 = (t >= d) ? hist[t - d] : 0;
        int v1 = hist[t + 256 - d];
        __syncthreads();
        hist[t] += v0; hist[t + 256] += v1;
        __syncthreads();
    }
    int e0 = hist[t] - orig[t];               // exclusive
    int e1 = hist[t + 256] - orig[t + 256];
    cur[t] = e0; cur[t + 256] = e1;
    rowptr[b * BKT + t] = bs + e0;
    rowptr[b * BKT + t + 256] = bs + e1;
    if (b == NB - 1 && t == 0) rowptr[NTOT2] = Eall;
    __syncthreads();
    for (int e = bs + t; e < be; e += 256) {
        int2 v = binned[e];
        int p = bs + atomicAdd(&cur[v.y & 511], 1);
        ss[p] = v.x;
    }
}

// ---------------- gather-mean: one wave per destination node -----------------
__global__ void gather_mean_k(const ushort* __restrict__ h, const int* __restrict__ rowptr,
                              const int* __restrict__ ssrc, ushort* __restrict__ out, int N)
{
    int i = blockIdx.x * 4 + (threadIdx.x >> 6);
    int lane = threadIdx.x & 63;
    int s0 = rowptr[i], s1 = rowptr[i + 1];
    float a0 = 0.f, a1 = 0.f;
    int e = s0;
    for (; e + 4 <= s1; e += 4) {
        int j0 = ssrc[e], j1 = ssrc[e + 1], j2 = ssrc[e + 2], j3 = ssrc[e + 3];
        uint32_t v0 = *(const uint32_t*)(h + (size_t)j0 * 128 + lane * 2);
        uint32_t v1 = *(const uint32_t*)(h + (size_t)j1 * 128 + lane * 2);
        uint32_t v2 = *(const uint32_t*)(h + (size_t)j2 * 128 + lane * 2);
        uint32_t v3 = *(const uint32_t*)(h + (size_t)j3 * 128 + lane * 2);
        a0 += bflo(v0) + bflo(v1) + bflo(v2) + bflo(v3);
        a1 += bfhi(v0) + bfhi(v1) + bfhi(v2) + bfhi(v3);
    }
    for (; e < s1; ++e) {
        uint32_t v = *(const uint32_t*)(h + (size_t)ssrc[e] * 128 + lane * 2);
        a0 += bflo(v);
        a1 += bfhi(v);
    }
    float inv = 1.0f / fmaxf((float)(s1 - s0), 1.0f);
    ushort2 o;
    o.x = f2bf(a0 * inv);
    o.y = f2bf(a1 * inv);
    *(ushort2*)(out + (size_t)i * 128 + lane * 2) = o;
}

// intra + inter means in one launch: waves [0,NP) -> outA, [NP,2NP) -> outB
__global__ void gather2_k(const ushort* __restrict__ hp, const int* __restrict__ rowptr,
                          const int* __restrict__ ssrc,
                          ushort* __restrict__ outA, ushort* __restrict__ outB)
{
    int g = blockIdx.x * 4 + (threadIdx.x >> 6);
    int lane = threadIdx.x & 63;
    ushort* out = (g < NP) ? outA : outB;
    int i = (g < NP) ? g : (g - NP);
    int s0 = rowptr[g], s1 = rowptr[g + 1];
    float a0 = 0.f, a1 = 0.f;
    int e = s0;
    for (; e + 4 <= s1; e += 4) {
        int j0 = ssrc[e], j1 = ssrc[e + 1], j2 = ssrc[e + 2], j3 = ssrc[e + 3];
        uint32_t v0 = *(const uint32_t*)(hp + (size_t)j0 * 128 + lane * 2);
        uint32_t v1 = *(const uint32_t*)(hp + (size_t)j1 * 128 + lane * 2);
        uint32_t v2 = *(const uint32_t*)(hp + (size_t)j2 * 128 + lane * 2);
        uint32_t v3 = *(const uint32_t*)(hp + (size_t)j3 * 128 + lane * 2);
        a0 += bflo(v0) + bflo(v1) + bflo(v2) + bflo(v3);
        a1 += bfhi(v0) + bfhi(v1) + bfhi(v2) + bfhi(v3);
    }
    for (; e < s1; ++e) {
        uint32_t v = *(const uint32_t*)(hp + (size_t)ssrc[e] * 128 + lane * 2);
        a0 += bflo(v);
        a1 += bfhi(v);
    }
    float inv = 1.0f / fmaxf((float)(s1 - s0), 1.0f);
    ushort2 o;
    o.x = f2bf(a0 * inv);
    o.y = f2bf(a1 * inv);
    *(ushort2*)(out + (size_t)i * 128 + lane * 2) = o;
}

// ---------------- multi-source GEMM: out = relu(sum_i A_i @ W_i + bias) ------
__launch_bounds__(256, 2)
__global__ void gemm_k(const ushort* __restrict__ A0, const ushort* __restrict__ A1,
                       const ushort* __restrict__ A2, const ushort* __restrict__ A3,
                       const ushort* __restrict__ W0, const ushort* __restrict__ W1,
                       const ushort* __restrict__ W2, const ushort* __restrict__ W3,
                       const float* __restrict__ bias, ushort* __restrict__ out, int nsrc)
{
    __shared__ ushort a_lds[128][72];
    __shared__ ushort w_lds[128][72];
    const int tid = threadIdx.x;
    const int lane = tid & 63, wave = tid >> 6;
    const int wr = wave >> 1, wc = wave & 1;
    const size_t r0 = (size_t)blockIdx.x * 128;

    f32x4 acc[4][4];
    const f32x4 zero = {0.f, 0.f, 0.f, 0.f};
#pragma unroll
    for (int m = 0; m < 4; ++m)
#pragma unroll
        for (int n = 0; n < 4; ++n) acc[m][n] = zero;

    const ushort* As[4] = {A0, A1, A2, A3};
    const ushort* Ws[4] = {W0, W1, W2, W3};

    for (int s = 0; s < nsrc; ++s) {
        const ushort* Ap = As[s] + r0 * 128;
        const ushort* Wp = Ws[s];
        for (int k0 = 0; k0 < 128; k0 += 64) {
            __syncthreads();
#pragma unroll
            for (int j = 0; j < 4; ++j) {
                int idx = (j * 256 + tid) * 8;
                int r = idx >> 6, c = idx & 63;
                *(uint4*)&a_lds[r][c] = *(const uint4*)(Ap + r * 128 + k0 + c);
                *(uint4*)&w_lds[r][c] = *(const uint4*)(Wp + r * 128 + k0 + c);
            }
            __syncthreads();
#pragma unroll
            for (int ks = 0; ks < 64; ks += 32) {
                short8 af[4], bfr[4];
                int col = ks + ((lane >> 4) << 3);
                int ra = (wr << 6) + (lane & 15);
                int rb = (wc << 6) + (lane & 15);
#pragma unroll
                for (int m = 0; m < 4; ++m) af[m] = *(const short8*)&a_lds[ra + m * 16][col];
#pragma unroll
                for (int n = 0; n < 4; ++n) bfr[n] = *(const short8*)&w_lds[rb + n * 16][col];
#pragma unroll
                for (int m = 0; m < 4; ++m)
#pragma unroll
                    for (int n = 0; n < 4; ++n)
                        acc[m][n] = __builtin_amdgcn_mfma_f32_16x16x32_bf16(
                            af[m], bfr[n], acc[m][n], 0, 0, 0);
            }
        }
    }

    const int rbase = (wr << 6) + ((lane >> 4) << 2);
    const int cbase = (wc << 6) + (lane & 15);
#pragma unroll
    for (int m = 0; m < 4; ++m)
#pragma unroll
        for (int n = 0; n < 4; ++n) {
            int coln = cbase + n * 16;
            float bcol = bias[coln];
#pragma unroll
            for (int rg = 0; rg < 4; ++rg) {
                int row = rbase + m * 16 + rg;
                float v = acc[m][n][rg] + bcol;
                v = fmaxf(v, 0.f);
                out[(r0 + row) * 128 + coln] = f2bf(v);
            }
        }
}

// ---------------- pooling gate: gate[i] = h_p[i]·Wg + bg ---------------------
__global__ void gate_k(const ushort* __restrict__ hp, const float* __restrict__ Wg,
                       const float* __restrict__ bg, float* __restrict__ gate)
{
    int lane = threadIdx.x & 63;
    int wave = threadIdx.x >> 6;
    int i = blockIdx.x * 4 + wave;
    ushort2 h2 = *(const ushort2*)(hp + (size_t)i * 128 + lane * 2);
    float2 w2 = *(const float2*)(Wg + lane * 2);
    float g = bf2f(h2.x) * w2.x + bf2f(h2.y) * w2.y;
    for (int off = 32; off; off >>= 1) g += __shfl_down(g, off);
    if (lane == 0) gate[i] = g + bg[0];
}

// ---------------- segment softmax + weighted sum -> emb[B,128] ---------------
__global__ void pool_k(const float* __restrict__ gate, const ushort* __restrict__ hp,
                       const int* __restrict__ batch,
                       float* __restrict__ ew, float* __restrict__ emb)
{
    __shared__ float red[256];
    __shared__ int sb[2];
    __shared__ float sm, sden;
    int b = blockIdx.x, t = threadIdx.x;
    if (t < 2) {
        int target = b + t;
        int lo = 0, hi = NP;
        while (lo < hi) { int mid = (lo + hi) >> 1; if (batch[mid] < target) lo = mid + 1; else hi = mid; }
        sb[t] = lo;
    }
    __syncthreads();
    int s = sb[0], e = sb[1];

    float lm = -3.4e38f;
    for (int i = s + t; i < e; i += 256) lm = fmaxf(lm, gate[i]);
    red[t] = lm; __syncthreads();
    for (int o = 128; o; o >>= 1) { if (t < o) red[t] = fmaxf(red[t], red[t + o]); __syncthreads(); }
    if (t == 0) sm = red[0];
    __syncthreads();
    float m = sm;

    float loc = 0.f;
    for (int i = s + t; i < e; i += 256) {
        float w = expf(gate[i] - m);
        ew[i] = w;
        loc += w;
    }
    red[t] = loc; __syncthreads();
    for (int o = 128; o; o >>= 1) { if (t < o) red[t] += red[t + o]; __syncthreads(); }
    if (t == 0) sden = red[0];
    __syncthreads();
    float inv = (e > s) ? 1.0f / sden : 0.f;

    int c = t & 127, half = t >> 7;
    float acc = 0.f;
    for (int i = s + half; i < e; i += 2) acc += ew[i] * bf2f(hp[(size_t)i * 128 + c]);
    __syncthreads();
    red[t] = acc; __syncthreads();
    if (t < 128) emb[b * 128 + c] = (red[c] + red[c + 128]) * inv;
}

// ---------------- actor/critic heads ----------------------------------------
__global__ void heads_k(const float* __restrict__ emb,
                        const float* __restrict__ Wa1, const float* __restrict__ ba1,
                        const float* __restrict__ Wa2, const float* __restrict__ ba2,
                        const float* __restrict__ Wc1, const float* __restrict__ bc1,
                        const float* __restrict__ Wc2, const float* __restrict__ bc2,
                        float* __restrict__ outL, float* __restrict__ outV)
{
    __shared__ float er[128], ha[128], hc[128], red[128];
    int b = blockIdx.x, t = threadIdx.x;
    if (t < 128) er[t] = emb[b * 128 + t];
    __syncthreads();
    if (t < 128) {
        float a = ba1[t];
        for (int k = 0; k < 128; ++k) a += er[k] * Wa1[k * 128 + t];
        ha[t] = fmaxf(a, 0.f);
    } else {
        int c = t - 128;
        float a = bc1[c];
        for (int k = 0; k < 128; ++k) a += er[k] * Wc1[k * 128 + c];
        hc[c] = fmaxf(a, 0.f);
    }
    __syncthreads();
    {
        float a = ba2[t];
        for (int k = 0; k < 128; ++k) a += ha[k] * Wa2[k * 256 + t];
        outL[b * 256 + t] = a;
    }
    if (t < 128) red[t] = hc[t] * Wc2[t];
    __syncthreads();
    for (int o = 64; o; o >>= 1) { if (t < o) red[t] += red[t + o]; __syncthreads(); }
    if (t == 0) outV[b] = red[0] + bc2[0];
}

// ============================================================================
extern "C" void kernel_launch(void* const* d_in, const int* in_sizes, int n_in,
                              void* d_out, int out_size, void* d_ws, size_t ws_size,
                              hipStream_t stream)
{
    const float* x_phys = (const float*)d_in[0];
    const float* x_log  = (const float*)d_in[1];
    const int*   batch  = (const int*)d_in[3];
    const int* intra_s = (const int*)d_in[4];  const int* intra_d = (const int*)d_in[5];
    const int* inter_s = (const int*)d_in[6];  const int* inter_d = (const int*)d_in[7];
    const int* map_s   = (const int*)d_in[8];  const int* map_d   = (const int*)d_in[9];
    const int E_INTRA = in_sizes[4], E_INTER = in_sizes[6], E_MAP = in_sizes[8];
    const int E_ALL = E_INTRA + E_INTER + E_MAP;

    const float* W_phys = (const float*)d_in[14]; const float* b_phys = (const float*)d_in[15];
    const float* W_log  = (const float*)d_in[16]; const float* b_log  = (const float*)d_in[17];
    const float* Wl1 = (const float*)d_in[20]; const float* bl1 = (const float*)d_in[21];
    const float* Wr1 = (const float*)d_in[22];
    const float* Wl2 = (const float*)d_in[23]; const float* bl2 = (const float*)d_in[24];
    const float* Wr2 = (const float*)d_in[25];
    const float* Wg  = (const float*)d_in[26]; const float* bg  = (const float*)d_in[27];
    const float* Wa1 = (const float*)d_in[28]; const float* ba1 = (const float*)d_in[29];
    const float* Wa2 = (const float*)d_in[30]; const float* ba2 = (const float*)d_in[31];
    const float* Wc1 = (const float*)d_in[32]; const float* bc1 = (const float*)d_in[33];
    const float* Wc2 = (const float*)d_in[34]; const float* bc2 = (const float*)d_in[35];

    float* outL = (float*)d_out;
    float* outV = outL + NBAT * AD;

    // ---- carve workspace ----
    char* wsp = (char*)d_ws;
    size_t off = 0;
    auto alloc = [&](size_t sz) -> void* {
        void* p = wsp + off;
        off = (off + sz + 255) & ~(size_t)255;
        return p;
    };
    ushort* hp    = (ushort*)alloc((size_t)NP * 128 * 2);
    ushort* hl    = (ushort*)alloc((size_t)NL * 128 * 2);
    ushort* aggbA = (ushort*)alloc((size_t)NP * 128 * 2);  // intra mean
    ushort* aggbB = (ushort*)alloc((size_t)NP * 128 * 2);  // inter mean
    ushort* Mmap  = (ushort*)alloc((size_t)NP * 128 * 2);  // mean(h_l) over map (static)

    // counting-sort CSR structures
    const int G1 = (E_ALL + EPB - 1) / EPB;       // bin-count/place blocks
    const int NSC = NB * G1;                       // count-matrix elements
    const int NPARTS = (NSC + 255) / 256;
    int*  cntMat   = (int*)alloc((size_t)NSC * 4);
    int*  partials = (int*)alloc((size_t)NPARTS * 4);
    int2* binned   = (int2*)alloc((size_t)E_ALL * 8);
    int*  rowptr   = (int*)alloc((size_t)(NTOT2 + 1) * 4);
    int*  ss       = (int*)alloc((size_t)E_ALL * 4);
    const int off_map = 2 * NP;

    float*  gate = (float*)alloc((size_t)NP * 4);
    float*  ew   = (float*)alloc((size_t)NP * 4);
    float*  emb  = (float*)alloc(NBAT * 128 * 4);
    ushort* wlt  = (ushort*)alloc((size_t)2 * 4 * 16384 * 2);
    float*  bsum = (float*)alloc(2 * 128 * 4);
    (void)ws_size; (void)out_size; (void)n_in;

    // ---- weight prep + encoders ----
    prep_w<<<9, 256, 0, stream>>>(Wl1, Wr1, bl1, Wl2, Wr2, bl2, wlt, bsum);
    encode_k<<<NP / 2, 256, 0, stream>>>(x_phys, W_phys, b_phys, hp, 5);
    encode_k<<<NL / 2, 256, 0, stream>>>(x_log, W_log, b_log, hl, 1);

    // ---- CSR build via LDS counting sort (once; reused both layers) ----
    binCount_k<<<G1, 256, 0, stream>>>(intra_d, inter_d, map_d,
                                       E_INTRA, E_INTER, E_MAP, G1, cntMat);
    scanA_k<<<NPARTS, 256, 0, stream>>>(cntMat, partials, NSC);
    scanB_k<<<1, 1024, 0, stream>>>(partials, NPARTS);
    scanC_k<<<NPARTS, 256, 0, stream>>>(cntMat, partials, NSC);
    binPlace_k<<<G1, 256, 0, stream>>>(intra_s, intra_d, inter_s, inter_d, map_s, map_d,
                                       E_INTRA, E_INTER, E_MAP, G1, cntMat, binned);
    csr_k<<<NB, 256, 0, stream>>>(binned, cntMat, G1, E_ALL, rowptr, ss);

    // ---- static map aggregation from h_l (reused by both layers) ----
    gather_mean_k<<<NP / 4, 256, 0, stream>>>(hl, rowptr + off_map, ss, Mmap, NP);

    // ---- two physical-node layers ----
    for (int l = 0; l < 2; ++l) {
        const ushort* wl = wlt + (size_t)l * 4 * 16384;
        const float* blp = bsum + l * 128;

        gather2_k<<<2 * NP / 4, 256, 0, stream>>>(hp, rowptr, ss, aggbA, aggbB);

        // out_p = relu(meanI@Wl0 + meanT@Wl1 + Mmap@Wl2 + hp@(Wr0+Wr1+Wr2) + blp)
        gemm_k<<<NP / 128, 256, 0, stream>>>(aggbA, aggbB, Mmap, hp,
                                             wl + 0 * 16384, wl + 1 * 16384,
                                             wl + 2 * 16384, wl + 3 * 16384,
                                             blp, hp, 4);
    }

    // ---- attentional pooling + heads ----
    gate_k<<<NP / 4, 256, 0, stream>>>(hp, Wg, bg, gate);
    pool_k<<<NBAT, 256, 0, stream>>>(gate, hp, batch, ew, emb);
    heads_k<<<NBAT, 256, 0, stream>>>(emb, Wa1, ba1, Wa2, ba2, Wc1, bc1, Wc2, bc2, outL, outV);
}

// Round 10
// 348.588 us; speedup vs baseline: 21.6993x; 1.1516x over previous
//
#include <hip/hip_runtime.h>
#include <stdint.h>

#define H    128
#define NBAT 128
#define AD   256
#define NP   65536
#define NL   32768
#define NTOT2 (3 * NP)              // intra | inter | map concatenated CSR nodes
#define NB   384                    // coarse buckets (dst >> 9)
#define BKT  512                    // nodes per bucket
#define EPB  4096                   // edges per bin-count/bin-place block
#define PNODES 64                   // nodes per wsum block

typedef __attribute__((ext_vector_type(8))) short short8;
typedef __attribute__((ext_vector_type(4))) float f32x4;

__device__ __forceinline__ ushort f2bf(float f) {
    uint32_t u = __float_as_uint(f);
    u += 0x7FFFu + ((u >> 16) & 1u);
    return (ushort)(u >> 16);
}
__device__ __forceinline__ float bf2f(ushort h) {
    return __uint_as_float(((uint32_t)h) << 16);
}
__device__ __forceinline__ float bflo(uint32_t v) { return __uint_as_float(v << 16); }
__device__ __forceinline__ float bfhi(uint32_t v) { return __uint_as_float(v & 0xFFFF0000u); }

// ---------------- weight prep (gate branch is dead code) ---------------------
__global__ void prep_w(const float* __restrict__ Wl1, const float* __restrict__ Wr1,
                       const float* __restrict__ bl1,
                       const float* __restrict__ Wl2, const float* __restrict__ Wr2,
                       const float* __restrict__ bl2,
                       ushort* __restrict__ wlt,  // [2][4][128*128] (n-major)
                       float* __restrict__ bsum)  // [2][128]
{
    int m = blockIdx.x;
    if (m < 8) {
        int l = m >> 2, r = m & 3;
        const float* Wl = l ? Wl2 : Wl1;
        const float* Wr = l ? Wr2 : Wr1;
        ushort* dst = wlt + (size_t)m * 16384;
        for (int it = 0; it < 64; ++it) {
            int idx = it * 256 + threadIdx.x;
            int k = idx >> 7, n = idx & 127;
            float v;
            if (r < 3) v = Wl[r * 16384 + k * 128 + n];
            else       v = Wr[0 * 16384 + k * 128 + n] + Wr[1 * 16384 + k * 128 + n]
                         + Wr[2 * 16384 + k * 128 + n];
            dst[n * 128 + k] = f2bf(v);
        }
    } else {
        int t = threadIdx.x;
        if (t < 128) {
            bsum[t]       = bl1[t] + bl1[128 + t] + bl1[256 + t];
            bsum[128 + t] = bl2[t] + bl2[128 + t] + bl2[256 + t];
        }
    }
}

// ---------------- encoders: h = relu(x @ W + b) -> bf16 ----------------------
__global__ void encode_k(const float* __restrict__ x, const float* __restrict__ W,
                         const float* __restrict__ b, ushort* __restrict__ out, int K)
{
    int t = threadIdx.x;
    int i = blockIdx.x * 2 + (t >> 7);
    int c = t & 127;
    float acc = b[c];
    for (int k = 0; k < K; ++k) acc += x[(size_t)i * K + k] * W[k * 128 + c];
    out[(size_t)i * 128 + c] = f2bf(fmaxf(acc, 0.f));
}

// ---------------- CSR build via two-level LDS counting sort ------------------
__global__ void binCount_k(const int* __restrict__ intra_d, const int* __restrict__ inter_d,
                           const int* __restrict__ map_d, int Ei, int Et, int Em,
                           int G1, int* __restrict__ cntMat /* [NB][G1] */)
{
    __shared__ int cnt[NB];
    int g = blockIdx.x, t = threadIdx.x;
    for (int b = t; b < NB; b += 256) cnt[b] = 0;
    __syncthreads();
    int Eall = Ei + Et + Em;
    int e0 = g * EPB, e1 = min(e0 + EPB, Eall);
    for (int e = e0 + t; e < e1; e += 256) {
        int d;
        if (e < Ei)           d = intra_d[e];
        else if (e < Ei + Et) d = NP + inter_d[e - Ei];
        else                  d = 2 * NP + map_d[e - Ei - Et];
        atomicAdd(&cnt[d >> 9], 1);
    }
    __syncthreads();
    for (int b = t; b < NB; b += 256) cntMat[b * G1 + g] = cnt[b];
}

__global__ void scanA_k(const int* __restrict__ data, int* __restrict__ partials, int n)
{
    __shared__ int red[256];
    int t = threadIdx.x;
    int idx = blockIdx.x * 256 + t;
    red[t] = (idx < n) ? data[idx] : 0;
    __syncthreads();
    for (int o = 128; o; o >>= 1) { if (t < o) red[t] += red[t + o]; __syncthreads(); }
    if (t == 0) partials[blockIdx.x] = red[0];
}

__global__ void scanB_k(int* __restrict__ partials, int np)
{
    __shared__ int lds[1024];
    int t = threadIdx.x;
    int v0 = (2 * t     < np) ? partials[2 * t]     : 0;
    int v1 = (2 * t + 1 < np) ? partials[2 * t + 1] : 0;
    lds[t] = v0 + v1;
    __syncthreads();
    for (int d = 1; d < 1024; d <<= 1) {
        int v = (t >= d) ? lds[t - d] : 0;
        __syncthreads();
        lds[t] += v;
        __syncthreads();
    }
    int base = (t == 0) ? 0 : lds[t - 1];
    if (2 * t     < np) partials[2 * t]     = base;
    if (2 * t + 1 < np) partials[2 * t + 1] = base + v0;
}

__global__ void scanC_k(int* __restrict__ data, const int* __restrict__ partials, int n)
{
    __shared__ int lds[256];
    int t = threadIdx.x;
    int idx = blockIdx.x * 256 + t;
    int v = (idx < n) ? data[idx] : 0;
    lds[t] = v;
    __syncthreads();
    for (int d = 1; d < 256; d <<= 1) {
        int x = (t >= d) ? lds[t - d] : 0;
        __syncthreads();
        lds[t] += x;
        __syncthreads();
    }
    if (idx < n) data[idx] = lds[t] - v + partials[blockIdx.x];  // exclusive, in-place
}

__global__ void binPlace_k(const int* __restrict__ intra_s, const int* __restrict__ intra_d,
                           const int* __restrict__ inter_s, const int* __restrict__ inter_d,
                           const int* __restrict__ map_s, const int* __restrict__ map_d,
                           int Ei, int Et, int Em, int G1,
                           const int* __restrict__ baseMat, int2* __restrict__ binned)
{
    __shared__ int cur[NB];
    int g = blockIdx.x, t = threadIdx.x;
    for (int b = t; b < NB; b += 256) cur[b] = baseMat[b * G1 + g];
    __syncthreads();
    int Eall = Ei + Et + Em;
    int e0 = g * EPB, e1 = min(e0 + EPB, Eall);
    for (int e = e0 + t; e < e1; e += 256) {
        int s, d;
        if (e < Ei)           { s = intra_s[e];          d = intra_d[e]; }
        else if (e < Ei + Et) { int k = e - Ei;      s = inter_s[k]; d = NP + inter_d[k]; }
        else                  { int k = e - Ei - Et; s = map_s[k];   d = 2 * NP + map_d[k]; }
        int p = atomicAdd(&cur[d >> 9], 1);
        binned[p] = make_int2(s, d);
    }
}

__global__ void csr_k(const int2* __restrict__ binned, const int* __restrict__ baseMat,
                      int G1, int Eall, int* __restrict__ rowptr, int* __restrict__ ss)
{
    __shared__ int hist[BKT], orig[BKT], cur[BKT];
    int b = blockIdx.x, t = threadIdx.x;
    int bs = baseMat[b * G1];
    int be = (b == NB - 1) ? Eall : baseMat[(b + 1) * G1];

    hist[t] = 0; hist[t + 256] = 0;
    __syncthreads();
    for (int e = bs + t; e < be; e += 256) atomicAdd(&hist[binned[e].y & 511], 1);
    __syncthreads();
    orig[t] = hist[t]; orig[t + 256] = hist[t + 256];
    __syncthreads();
    for (int d = 1; d < 512; d <<= 1) {
        int v0 = (t >= d) ? hist[t - d] : 0;
        int v1 = hist[t + 256 - d];
        __syncthreads();
        hist[t] += v0; hist[t + 256] += v1;
        __syncthreads();
    }
    int e0 = hist[t] - orig[t];
    int e1 = hist[t + 256] - orig[t + 256];
    cur[t] = e0; cur[t + 256] = e1;
    rowptr[b * BKT + t] = bs + e0;
    rowptr[b * BKT + t + 256] = bs + e1;
    if (b == NB - 1 && t == 0) rowptr[NTOT2] = Eall;
    __syncthreads();
    for (int e = bs + t; e < be; e += 256) {
        int2 v = binned[e];
        int p = bs + atomicAdd(&cur[v.y & 511], 1);
        ss[p] = v.x;
    }
}

// ---------------- gather-mean: one wave per destination node -----------------
__global__ void gather_mean_k(const ushort* __restrict__ h, const int* __restrict__ rowptr,
                              const int* __restrict__ ssrc, ushort* __restrict__ out, int N)
{
    int i = blockIdx.x * 4 + (threadIdx.x >> 6);
    int lane = threadIdx.x & 63;
    int s0 = rowptr[i], s1 = rowptr[i + 1];
    float a0 = 0.f, a1 = 0.f;
    int e = s0;
    for (; e + 4 <= s1; e += 4) {
        int j0 = ssrc[e], j1 = ssrc[e + 1], j2 = ssrc[e + 2], j3 = ssrc[e + 3];
        uint32_t v0 = *(const uint32_t*)(h + (size_t)j0 * 128 + lane * 2);
        uint32_t v1 = *(const uint32_t*)(h + (size_t)j1 * 128 + lane * 2);
        uint32_t v2 = *(const uint32_t*)(h + (size_t)j2 * 128 + lane * 2);
        uint32_t v3 = *(const uint32_t*)(h + (size_t)j3 * 128 + lane * 2);
        a0 += bflo(v0) + bflo(v1) + bflo(v2) + bflo(v3);
        a1 += bfhi(v0) + bfhi(v1) + bfhi(v2) + bfhi(v3);
    }
    for (; e < s1; ++e) {
        uint32_t v = *(const uint32_t*)(h + (size_t)ssrc[e] * 128 + lane * 2);
        a0 += bflo(v);
        a1 += bfhi(v);
    }
    float inv = 1.0f / fmaxf((float)(s1 - s0), 1.0f);
    ushort2 o;
    o.x = f2bf(a0 * inv);
    o.y = f2bf(a1 * inv);
    *(ushort2*)(out + (size_t)i * 128 + lane * 2) = o;
}

// intra + inter means in one launch: waves [0,NP) -> outA, [NP,2NP) -> outB
__global__ void gather2_k(const ushort* __restrict__ hp, const int* __restrict__ rowptr,
                          const int* __restrict__ ssrc,
                          ushort* __restrict__ outA, ushort* __restrict__ outB)
{
    int g = blockIdx.x * 4 + (threadIdx.x >> 6);
    int lane = threadIdx.x & 63;
    ushort* out = (g < NP) ? outA : outB;
    int i = (g < NP) ? g : (g - NP);
    int s0 = rowptr[g], s1 = rowptr[g + 1];
    float a0 = 0.f, a1 = 0.f;
    int e = s0;
    for (; e + 4 <= s1; e += 4) {
        int j0 = ssrc[e], j1 = ssrc[e + 1], j2 = ssrc[e + 2], j3 = ssrc[e + 3];
        uint32_t v0 = *(const uint32_t*)(hp + (size_t)j0 * 128 + lane * 2);
        uint32_t v1 = *(const uint32_t*)(hp + (size_t)j1 * 128 + lane * 2);
        uint32_t v2 = *(const uint32_t*)(hp + (size_t)j2 * 128 + lane * 2);
        uint32_t v3 = *(const uint32_t*)(hp + (size_t)j3 * 128 + lane * 2);
        a0 += bflo(v0) + bflo(v1) + bflo(v2) + bflo(v3);
        a1 += bfhi(v0) + bfhi(v1) + bfhi(v2) + bfhi(v3);
    }
    for (; e < s1; ++e) {
        uint32_t v = *(const uint32_t*)(hp + (size_t)ssrc[e] * 128 + lane * 2);
        a0 += bflo(v);
        a1 += bfhi(v);
    }
    float inv = 1.0f / fmaxf((float)(s1 - s0), 1.0f);
    ushort2 o;
    o.x = f2bf(a0 * inv);
    o.y = f2bf(a1 * inv);
    *(ushort2*)(out + (size_t)i * 128 + lane * 2) = o;
}

// ---------------- multi-source GEMM: out = relu(sum_i A_i @ W_i + bias) ------
__launch_bounds__(256, 2)
__global__ void gemm_k(const ushort* __restrict__ A0, const ushort* __restrict__ A1,
                       const ushort* __restrict__ A2, const ushort* __restrict__ A3,
                       const ushort* __restrict__ W0, const ushort* __restrict__ W1,
                       const ushort* __restrict__ W2, const ushort* __restrict__ W3,
                       const float* __restrict__ bias, ushort* __restrict__ out, int nsrc)
{
    __shared__ ushort a_lds[128][72];
    __shared__ ushort w_lds[128][72];
    const int tid = threadIdx.x;
    const int lane = tid & 63, wave = tid >> 6;
    const int wr = wave >> 1, wc = wave & 1;
    const size_t r0 = (size_t)blockIdx.x * 128;

    f32x4 acc[4][4];
    const f32x4 zero = {0.f, 0.f, 0.f, 0.f};
#pragma unroll
    for (int m = 0; m < 4; ++m)
#pragma unroll
        for (int n = 0; n < 4; ++n) acc[m][n] = zero;

    const ushort* As[4] = {A0, A1, A2, A3};
    const ushort* Ws[4] = {W0, W1, W2, W3};

    for (int s = 0; s < nsrc; ++s) {
        const ushort* Ap = As[s] + r0 * 128;
        const ushort* Wp = Ws[s];
        for (int k0 = 0; k0 < 128; k0 += 64) {
            __syncthreads();
#pragma unroll
            for (int j = 0; j < 4; ++j) {
                int idx = (j * 256 + tid) * 8;
                int r = idx >> 6, c = idx & 63;
                *(uint4*)&a_lds[r][c] = *(const uint4*)(Ap + r * 128 + k0 + c);
                *(uint4*)&w_lds[r][c] = *(const uint4*)(Wp + r * 128 + k0 + c);
            }
            __syncthreads();
#pragma unroll
            for (int ks = 0; ks < 64; ks += 32) {
                short8 af[4], bfr[4];
                int col = ks + ((lane >> 4) << 3);
                int ra = (wr << 6) + (lane & 15);
                int rb = (wc << 6) + (lane & 15);
#pragma unroll
                for (int m = 0; m < 4; ++m) af[m] = *(const short8*)&a_lds[ra + m * 16][col];
#pragma unroll
                for (int n = 0; n < 4; ++n) bfr[n] = *(const short8*)&w_lds[rb + n * 16][col];
#pragma unroll
                for (int m = 0; m < 4; ++m)
#pragma unroll
                    for (int n = 0; n < 4; ++n)
                        acc[m][n] = __builtin_amdgcn_mfma_f32_16x16x32_bf16(
                            af[m], bfr[n], acc[m][n], 0, 0, 0);
            }
        }
    }

    const int rbase = (wr << 6) + ((lane >> 4) << 2);
    const int cbase = (wc << 6) + (lane & 15);
#pragma unroll
    for (int m = 0; m < 4; ++m)
#pragma unroll
        for (int n = 0; n < 4; ++n) {
            int coln = cbase + n * 16;
            float bcol = bias[coln];
#pragma unroll
            for (int rg = 0; rg < 4; ++rg) {
                int row = rbase + m * 16 + rg;
                float v = acc[m][n][rg] + bcol;
                v = fmaxf(v, 0.f);
                out[(r0 + row) * 128 + coln] = f2bf(v);
            }
        }
}

// ---------------- pooling gate: gate[i] = h_p[i]·Wg + bg ---------------------
__global__ void gate_k(const ushort* __restrict__ hp, const float* __restrict__ Wg,
                       const float* __restrict__ bg, float* __restrict__ gate)
{
    int lane = threadIdx.x & 63;
    int wave = threadIdx.x >> 6;
    int i = blockIdx.x * 4 + wave;
    ushort2 h2 = *(const ushort2*)(hp + (size_t)i * 128 + lane * 2);
    float2 w2 = *(const float2*)(Wg + lane * 2);
    float g = bf2f(h2.x) * w2.x + bf2f(h2.y) * w2.y;
    for (int off = 32; off; off >>= 1) g += __shfl_down(g, off);
    if (lane == 0) gate[i] = g + bg[0];
}

// ---------------- per-batch softmax stats: m[b], 1/den[b] --------------------
__global__ void seg_stat_k(const float* __restrict__ gate, const int* __restrict__ batch,
                           float* __restrict__ mden /* [2*NBAT]: m | invden */)
{
    __shared__ float red[256];
    __shared__ int sb[2];
    __shared__ float sm;
    int b = blockIdx.x, t = threadIdx.x;
    if (t < 2) {
        int target = b + t;
        int lo = 0, hi = NP;
        while (lo < hi) { int mid = (lo + hi) >> 1; if (batch[mid] < target) lo = mid + 1; else hi = mid; }
        sb[t] = lo;
    }
    __syncthreads();
    int s = sb[0], e = sb[1];

    float lm = -3.4e38f;
    for (int i = s + t; i < e; i += 256) lm = fmaxf(lm, gate[i]);
    red[t] = lm; __syncthreads();
    for (int o = 128; o; o >>= 1) { if (t < o) red[t] = fmaxf(red[t], red[t + o]); __syncthreads(); }
    if (t == 0) sm = red[0];
    __syncthreads();
    float m = sm;

    float loc = 0.f;
    for (int i = s + t; i < e; i += 256) loc += __expf(gate[i] - m);
    red[t] = loc; __syncthreads();
    for (int o = 128; o; o >>= 1) { if (t < o) red[t] += red[t + o]; __syncthreads(); }
    if (t == 0) {
        mden[b] = m;
        mden[NBAT + b] = (e > s) ? 1.0f / red[0] : 0.f;
    }
}

// ---------------- weighted segment sum: emb[b] += alpha_i * h_p[i] -----------
// 1024 blocks x 64 nodes; batch[] is sorted so each thread flushes its fp32
// partial to global atomics only at segment boundaries (~1.3 flushes/thread).
__global__ void wsum_k(const ushort* __restrict__ hp, const float* __restrict__ gate,
                       const int* __restrict__ batch, const float* __restrict__ mden,
                       float* __restrict__ emb)
{
    int n0 = blockIdx.x * PNODES;
    int t = threadIdx.x;
    int c2 = (t & 63) * 2;          // channel pair
    int slice = t >> 6;             // 0..3, node stride 4
    float a0 = 0.f, a1 = 0.f;
    int curb = batch[n0 + slice];
    for (int i = n0 + slice; i < n0 + PNODES; i += 4) {
        int b = batch[i];
        if (b != curb) {
            atomicAdd(&emb[curb * 128 + c2], a0);
            atomicAdd(&emb[curb * 128 + c2 + 1], a1);
            a0 = a1 = 0.f;
            curb = b;
        }
        float w = __expf(gate[i] - mden[curb]) * mden[NBAT + curb];
        uint32_t v = *(const uint32_t*)(hp + (size_t)i * 128 + c2);
        a0 += w * bflo(v);
        a1 += w * bfhi(v);
    }
    atomicAdd(&emb[curb * 128 + c2], a0);
    atomicAdd(&emb[curb * 128 + c2 + 1], a1);
}

// ---------------- actor/critic heads ----------------------------------------
__global__ void heads_k(const float* __restrict__ emb,
                        const float* __restrict__ Wa1, const float* __restrict__ ba1,
                        const float* __restrict__ Wa2, const float* __restrict__ ba2,
                        const float* __restrict__ Wc1, const float* __restrict__ bc1,
                        const float* __restrict__ Wc2, const float* __restrict__ bc2,
                        float* __restrict__ outL, float* __restrict__ outV)
{
    __shared__ float er[128], ha[128], hc[128], red[128];
    int b = blockIdx.x, t = threadIdx.x;
    if (t < 128) er[t] = emb[b * 128 + t];
    __syncthreads();
    if (t < 128) {
        float a = ba1[t];
        for (int k = 0; k < 128; ++k) a += er[k] * Wa1[k * 128 + t];
        ha[t] = fmaxf(a, 0.f);
    } else {
        int c = t - 128;
        float a = bc1[c];
        for (int k = 0; k < 128; ++k) a += er[k] * Wc1[k * 128 + c];
        hc[c] = fmaxf(a, 0.f);
    }
    __syncthreads();
    {
        float a = ba2[t];
        for (int k = 0; k < 128; ++k) a += ha[k] * Wa2[k * 256 + t];
        outL[b * 256 + t] = a;
    }
    if (t < 128) red[t] = hc[t] * Wc2[t];
    __syncthreads();
    for (int o = 64; o; o >>= 1) { if (t < o) red[t] += red[t + o]; __syncthreads(); }
    if (t == 0) outV[b] = red[0] + bc2[0];
}

// ============================================================================
extern "C" void kernel_launch(void* const* d_in, const int* in_sizes, int n_in,
                              void* d_out, int out_size, void* d_ws, size_t ws_size,
                              hipStream_t stream)
{
    const float* x_phys = (const float*)d_in[0];
    const float* x_log  = (const float*)d_in[1];
    const int*   batch  = (const int*)d_in[3];
    const int* intra_s = (const int*)d_in[4];  const int* intra_d = (const int*)d_in[5];
    const int* inter_s = (const int*)d_in[6];  const int* inter_d = (const int*)d_in[7];
    const int* map_s   = (const int*)d_in[8];  const int* map_d   = (const int*)d_in[9];
    const int E_INTRA = in_sizes[4], E_INTER = in_sizes[6], E_MAP = in_sizes[8];
    const int E_ALL = E_INTRA + E_INTER + E_MAP;

    const float* W_phys = (const float*)d_in[14]; const float* b_phys = (const float*)d_in[15];
    const float* W_log  = (const float*)d_in[16]; const float* b_log  = (const float*)d_in[17];
    const float* Wl1 = (const float*)d_in[20]; const float* bl1 = (const float*)d_in[21];
    const float* Wr1 = (const float*)d_in[22];
    const float* Wl2 = (const float*)d_in[23]; const float* bl2 = (const float*)d_in[24];
    const float* Wr2 = (const float*)d_in[25];
    const float* Wg  = (const float*)d_in[26]; const float* bg  = (const float*)d_in[27];
    const float* Wa1 = (const float*)d_in[28]; const float* ba1 = (const float*)d_in[29];
    const float* Wa2 = (const float*)d_in[30]; const float* ba2 = (const float*)d_in[31];
    const float* Wc1 = (const float*)d_in[32]; const float* bc1 = (const float*)d_in[33];
    const float* Wc2 = (const float*)d_in[34]; const float* bc2 = (const float*)d_in[35];

    float* outL = (float*)d_out;
    float* outV = outL + NBAT * AD;

    // ---- carve workspace ----
    char* wsp = (char*)d_ws;
    size_t off = 0;
    auto alloc = [&](size_t sz) -> void* {
        void* p = wsp + off;
        off = (off + sz + 255) & ~(size_t)255;
        return p;
    };
    ushort* hp    = (ushort*)alloc((size_t)NP * 128 * 2);
    ushort* hl    = (ushort*)alloc((size_t)NL * 128 * 2);
    ushort* aggbA = (ushort*)alloc((size_t)NP * 128 * 2);
    ushort* aggbB = (ushort*)alloc((size_t)NP * 128 * 2);
    ushort* Mmap  = (ushort*)alloc((size_t)NP * 128 * 2);

    // counting-sort CSR structures
    const int G1 = (E_ALL + EPB - 1) / EPB;
    const int NSC = NB * G1;
    const int NPARTS = (NSC + 255) / 256;
    int*  cntMat   = (int*)alloc((size_t)NSC * 4);
    int*  partials = (int*)alloc((size_t)NPARTS * 4);
    int2* binned   = (int2*)alloc((size_t)E_ALL * 8);
    int*  rowptr   = (int*)alloc((size_t)(NTOT2 + 1) * 4);
    int*  ss       = (int*)alloc((size_t)E_ALL * 4);
    const int off_map = 2 * NP;

    float*  gate = (float*)alloc((size_t)NP * 4);
    float*  mden = (float*)alloc(2 * NBAT * 4);
    float*  emb  = (float*)alloc(NBAT * 128 * 4);
    ushort* wlt  = (ushort*)alloc((size_t)2 * 4 * 16384 * 2);
    float*  bsum = (float*)alloc(2 * 128 * 4);
    (void)ws_size; (void)out_size; (void)n_in;

    // ---- weight prep + encoders ----
    prep_w<<<9, 256, 0, stream>>>(Wl1, Wr1, bl1, Wl2, Wr2, bl2, wlt, bsum);
    encode_k<<<NP / 2, 256, 0, stream>>>(x_phys, W_phys, b_phys, hp, 5);
    encode_k<<<NL / 2, 256, 0, stream>>>(x_log, W_log, b_log, hl, 1);

    // ---- CSR build via LDS counting sort (once; reused both layers) ----
    binCount_k<<<G1, 256, 0, stream>>>(intra_d, inter_d, map_d,
                                       E_INTRA, E_INTER, E_MAP, G1, cntMat);
    scanA_k<<<NPARTS, 256, 0, stream>>>(cntMat, partials, NSC);
    scanB_k<<<1, 1024, 0, stream>>>(partials, NPARTS);
    scanC_k<<<NPARTS, 256, 0, stream>>>(cntMat, partials, NSC);
    binPlace_k<<<G1, 256, 0, stream>>>(intra_s, intra_d, inter_s, inter_d, map_s, map_d,
                                       E_INTRA, E_INTER, E_MAP, G1, cntMat, binned);
    csr_k<<<NB, 256, 0, stream>>>(binned, cntMat, G1, E_ALL, rowptr, ss);

    // ---- static map aggregation from h_l (reused by both layers) ----
    gather_mean_k<<<NP / 4, 256, 0, stream>>>(hl, rowptr + off_map, ss, Mmap, NP);

    // ---- two physical-node layers ----
    for (int l = 0; l < 2; ++l) {
        const ushort* wl = wlt + (size_t)l * 4 * 16384;
        const float* blp = bsum + l * 128;

        gather2_k<<<2 * NP / 4, 256, 0, stream>>>(hp, rowptr, ss, aggbA, aggbB);

        gemm_k<<<NP / 128, 256, 0, stream>>>(aggbA, aggbB, Mmap, hp,
                                             wl + 0 * 16384, wl + 1 * 16384,
                                             wl + 2 * 16384, wl + 3 * 16384,
                                             blp, hp, 4);
    }

    // ---- attentional pooling + heads ----
    gate_k<<<NP / 4, 256, 0, stream>>>(hp, Wg, bg, gate);
    seg_stat_k<<<NBAT, 256, 0, stream>>>(gate, batch, mden);
    hipMemsetAsync(emb, 0, (size_t)NBAT * 128 * 4, stream);
    wsum_k<<<NP / PNODES, 256, 0, stream>>>(hp, gate, batch, mden, emb);
    heads_k<<<NBAT, 256, 0, stream>>>(emb, Wa1, ba1, Wa2, ba2, Wc1, bc1, Wc2, bc2, outL, outV);
}